// Round 1
// baseline (2290.622 us; speedup 1.0000x reference)
//
#include <hip/hip_runtime.h>
#include <math.h>

constexpr int HID = 1024;
constexpr int HEADS = 8;
constexpr float NEG_SLOPE = 0.2f;
constexpr float EPSV = 1e-16f;

__device__ __forceinline__ float4 ld4(const float* p){ return *reinterpret_cast<const float4*>(p); }

// ---------------- fp32 tiled GEMM: C = act(A[M,K] @ W[K,N] + bias[N]) ----------------
// ACT: 0 = none, 1 = relu, 2 = elu
template<int ACT>
__global__ __launch_bounds__(256) void gemm_bias_act(
    const float* __restrict__ A, const float* __restrict__ W,
    const float* __restrict__ bias, float* __restrict__ C,
    int M, int K, int N)
{
  __shared__ __align__(16) float As[16][64];
  __shared__ __align__(16) float Bs[16][64];
  const int tid = threadIdx.x;
  const int tx = tid & 15, ty = tid >> 4;
  const int bm = blockIdx.y * 64, bn = blockIdx.x * 64;
  float acc[4][4] = {};
  const int ar = tid >> 2, akq = (tid & 3) * 4;   // A-tile loader: row 0..63, k-quad
  const int wk = tid >> 4, wn = (tid & 15) * 4;   // W-tile loader: k-row 0..15, col-quad

  for (int k0 = 0; k0 < K; k0 += 16) {
    float4 av = make_float4(0.f,0.f,0.f,0.f);
    if (bm + ar < M) av = ld4(&A[(size_t)(bm + ar) * K + k0 + akq]);
    As[akq+0][ar] = av.x; As[akq+1][ar] = av.y; As[akq+2][ar] = av.z; As[akq+3][ar] = av.w;
    *reinterpret_cast<float4*>(&Bs[wk][wn]) = ld4(&W[(size_t)(k0 + wk) * N + bn + wn]);
    __syncthreads();
    #pragma unroll
    for (int k = 0; k < 16; ++k) {
      const float4 a4 = *reinterpret_cast<const float4*>(&As[k][ty*4]);
      const float4 b4 = *reinterpret_cast<const float4*>(&Bs[k][tx*4]);
      const float a0=a4.x,a1=a4.y,a2=a4.z,a3=a4.w;
      const float b0=b4.x,b1=b4.y,b2=b4.z,b3=b4.w;
      acc[0][0]+=a0*b0; acc[0][1]+=a0*b1; acc[0][2]+=a0*b2; acc[0][3]+=a0*b3;
      acc[1][0]+=a1*b0; acc[1][1]+=a1*b1; acc[1][2]+=a1*b2; acc[1][3]+=a1*b3;
      acc[2][0]+=a2*b0; acc[2][1]+=a2*b1; acc[2][2]+=a2*b2; acc[2][3]+=a2*b3;
      acc[3][0]+=a3*b0; acc[3][1]+=a3*b1; acc[3][2]+=a3*b2; acc[3][3]+=a3*b3;
    }
    __syncthreads();
  }

  const float4 bb = ld4(&bias[bn + tx*4]);
  const float bv[4] = {bb.x, bb.y, bb.z, bb.w};
  #pragma unroll
  for (int i = 0; i < 4; ++i) {
    const int row = bm + ty*4 + i;
    if (row >= M) break;
    float v[4];
    #pragma unroll
    for (int j = 0; j < 4; ++j) {
      float t = acc[i][j] + bv[j];
      if (ACT == 1) t = fmaxf(t, 0.f);
      else if (ACT == 2) t = (t > 0.f) ? t : expm1f(t);
      v[j] = t;
    }
    *reinterpret_cast<float4*>(&C[(size_t)row * N + bn + tx*4]) = make_float4(v[0],v[1],v[2],v[3]);
  }
}

// ---------------- CSR build ----------------
__global__ void count_deg(const int* __restrict__ dst, int* __restrict__ deg, int E){
  int e = blockIdx.x * blockDim.x + threadIdx.x;
  if (e < E) atomicAdd(&deg[dst[e]], 1);
}

__global__ __launch_bounds__(1024) void scan_offsets(const int* __restrict__ deg, int* __restrict__ offs, int n){
  __shared__ int sd[1024];
  const int tid = threadIdx.x;
  int running = 0;
  for (int base = 0; base < n; base += 1024){
    const int i = base + tid;
    const int v = (i < n) ? deg[i] : 0;
    sd[tid] = v;
    __syncthreads();
    for (int s = 1; s < 1024; s <<= 1){
      int t = (tid >= s) ? sd[tid - s] : 0;
      __syncthreads();
      sd[tid] += t;
      __syncthreads();
    }
    if (i < n) offs[i] = running + sd[tid] - v;   // exclusive
    running += sd[1023];
    __syncthreads();
  }
  if (tid == 0) offs[n] = running;
}

__global__ void fill_csr(const int* __restrict__ src, const int* __restrict__ dst,
                         const int* __restrict__ offs, int* __restrict__ cursor,
                         int* __restrict__ csr_eid, int* __restrict__ csr_src, int E){
  int e = blockIdx.x * blockDim.x + threadIdx.x;
  if (e < E){
    int d = dst[e];
    int pos = offs[d] + atomicAdd(&cursor[d], 1);
    csr_eid[pos] = e;
    csr_src[pos] = src[e];
  }
}

// ---------------- edge logits: one wave per edge ----------------
// logits[e][h] = sum_d lrelu(xl[src][d] + xr[dst][d] + (edge_attr@We)[d]) * att_flat[d], d in head h
__global__ __launch_bounds__(256) void edge_logits(
    const int* __restrict__ src, const int* __restrict__ dst,
    const float* __restrict__ edge_attr, const float* __restrict__ We,
    const float* __restrict__ att, const float* __restrict__ xl,
    const float* __restrict__ xr, float* __restrict__ logits, int E)
{
  const int e = blockIdx.x * (blockDim.x >> 6) + (threadIdx.x >> 6);
  const int lane = threadIdx.x & 63;
  if (e >= E) return;
  const int s = src[e], d = dst[e];
  const float4 ea = ld4(&edge_attr[(size_t)e * 4]);
  const float* xls = xl + (size_t)s * HID;
  const float* xrd = xr + (size_t)d * HID;
  float acc[4];
  #pragma unroll
  for (int p = 0; p < 4; ++p){
    const int base = p * 256 + lane * 4;
    const float4 a  = ld4(xls + base);
    const float4 bx = ld4(xrd + base);
    const float4 w0 = ld4(We + base);
    const float4 w1 = ld4(We + 1024 + base);
    const float4 w2 = ld4(We + 2048 + base);
    const float4 w3 = ld4(We + 3072 + base);
    const float4 at = ld4(att + base);
    float sum = 0.f;
    {
      float v = a.x + bx.x + ea.x*w0.x + ea.y*w1.x + ea.z*w2.x + ea.w*w3.x;
      v = (v > 0.f) ? v : NEG_SLOPE * v;  sum += v * at.x;
    }
    {
      float v = a.y + bx.y + ea.x*w0.y + ea.y*w1.y + ea.z*w2.y + ea.w*w3.y;
      v = (v > 0.f) ? v : NEG_SLOPE * v;  sum += v * at.y;
    }
    {
      float v = a.z + bx.z + ea.x*w0.z + ea.y*w1.z + ea.z*w2.z + ea.w*w3.z;
      v = (v > 0.f) ? v : NEG_SLOPE * v;  sum += v * at.z;
    }
    {
      float v = a.w + bx.w + ea.x*w0.w + ea.y*w1.w + ea.z*w2.w + ea.w*w3.w;
      v = (v > 0.f) ? v : NEG_SLOPE * v;  sum += v * at.w;
    }
    acc[p] = sum;
  }
  // reduce within each 32-lane half (head = 2p for lanes<32, 2p+1 for lanes>=32)
  #pragma unroll
  for (int m = 1; m <= 16; m <<= 1){
    #pragma unroll
    for (int p = 0; p < 4; ++p) acc[p] += __shfl_xor(acc[p], m, 64);
  }
  if (lane == 0){
    #pragma unroll
    for (int p = 0; p < 4; ++p) logits[(size_t)e * 8 + 2*p] = acc[p];
  } else if (lane == 32){
    #pragma unroll
    for (int p = 0; p < 4; ++p) logits[(size_t)e * 8 + 2*p + 1] = acc[p];
  }
}

// ---------------- per-(node,head) softmax; rewrites logits in place with alpha ----------------
__global__ void node_softmax(const int* __restrict__ offs, const int* __restrict__ csr_eid,
                             float* __restrict__ la, int N)
{
  const int idx = blockIdx.x * blockDim.x + threadIdx.x;
  if (idx >= N * HEADS) return;
  const int n = idx >> 3, h = idx & 7;
  const int o0 = offs[n], o1 = offs[n + 1];
  float mx = -INFINITY;
  for (int i = o0; i < o1; ++i) mx = fmaxf(mx, la[(size_t)csr_eid[i] * 8 + h]);
  const float lm = (o1 > o0) ? mx : 0.f;   // isfinite fix
  float ssum = 0.f;
  for (int i = o0; i < o1; ++i) ssum += expf(la[(size_t)csr_eid[i] * 8 + h] - lm);
  const float rd = 1.f / (ssum + EPSV);
  for (int i = o0; i < o1; ++i){
    const size_t p = (size_t)csr_eid[i] * 8 + h;
    la[p] = expf(la[p] - lm) * rd;
  }
}

// ---------------- aggregation: block per node, out = elu(sum alpha*xl[src] + bias) ----------------
__global__ __launch_bounds__(256) void aggregate(
    const int* __restrict__ offs, const int* __restrict__ csr_eid, const int* __restrict__ csr_src,
    const float* __restrict__ alpha, const float* __restrict__ xl,
    const float* __restrict__ bias, float* __restrict__ out, int N)
{
  const int n = blockIdx.x;
  const int t = threadIdx.x;
  const int h = t >> 5;                 // dims t*4..t*4+3 all in head t>>5
  const int o0 = offs[n], o1 = offs[n + 1];
  float4 acc = make_float4(0.f,0.f,0.f,0.f);
  for (int i = o0; i < o1; ++i){
    const int eid = csr_eid[i], s = csr_src[i];
    const float al = alpha[(size_t)eid * 8 + h];
    const float4 v = ld4(&xl[(size_t)s * HID + t*4]);
    acc.x += v.x * al; acc.y += v.y * al; acc.z += v.z * al; acc.w += v.w * al;
  }
  const float4 bb = ld4(&bias[t*4]);
  float o[4] = {acc.x + bb.x, acc.y + bb.y, acc.z + bb.z, acc.w + bb.w};
  #pragma unroll
  for (int j = 0; j < 4; ++j) o[j] = (o[j] > 0.f) ? o[j] : expm1f(o[j]);
  *reinterpret_cast<float4*>(&out[(size_t)n * HID + t*4]) = make_float4(o[0],o[1],o[2],o[3]);
}

// ---------------- final matvec + sigmoid: one wave per row ----------------
__global__ __launch_bounds__(256) void mlp_final(const float* __restrict__ h, const float* __restrict__ w,
                                                 const float* __restrict__ b, float* __restrict__ out, int M)
{
  const int row = (int)((blockIdx.x * (size_t)blockDim.x + threadIdx.x) >> 6);
  const int lane = threadIdx.x & 63;
  if (row >= M) return;
  const float2 v  = *reinterpret_cast<const float2*>(&h[(size_t)row * 128 + lane * 2]);
  const float2 ww = *reinterpret_cast<const float2*>(&w[lane * 2]);
  float s = v.x * ww.x + v.y * ww.y;
  #pragma unroll
  for (int m = 1; m <= 32; m <<= 1) s += __shfl_xor(s, m, 64);
  if (lane == 0) out[row] = 1.f / (1.f + expf(-(s + b[0])));
}

extern "C" void kernel_launch(void* const* d_in, const int* in_sizes, int n_in,
                              void* d_out, int out_size, void* d_ws, size_t ws_size,
                              hipStream_t stream)
{
  const float* x        = (const float*)d_in[0];
  const int*   ei       = (const int*)d_in[1];
  const float* edge_attr= (const float*)d_in[2];
  const float* W_in     = (const float*)d_in[3];
  const float* b_in     = (const float*)d_in[4];
  const float* m1_W     = (const float*)d_in[5];
  const float* m1_b     = (const float*)d_in[6];
  const float* m2_W     = (const float*)d_in[7];
  const float* m2_b     = (const float*)d_in[8];
  const float* m3_W     = (const float*)d_in[9];
  const float* m3_b     = (const float*)d_in[10];
  const float* g_Wl[2]  = {(const float*)d_in[11], (const float*)d_in[18]};
  const float* g_bl[2]  = {(const float*)d_in[12], (const float*)d_in[19]};
  const float* g_Wr[2]  = {(const float*)d_in[13], (const float*)d_in[20]};
  const float* g_br[2]  = {(const float*)d_in[14], (const float*)d_in[21]};
  const float* g_We[2]  = {(const float*)d_in[15], (const float*)d_in[22]};
  const float* g_att[2] = {(const float*)d_in[16], (const float*)d_in[23]};
  const float* g_b[2]   = {(const float*)d_in[17], (const float*)d_in[24]};

  const int N = in_sizes[0] / 1024;
  const int E = in_sizes[1] / 2;
  const int* src  = ei;
  const int* dstv = ei + E;
  float* out = (float*)d_out;

  char* wsp = (char*)d_ws;
  size_t off = 0;
  auto alloc = [&](size_t bytes)->char* {
    char* p = wsp + off;
    off = (off + bytes + 255) & ~(size_t)255;
    return p;
  };
  float* Abuf   = (float*)alloc((size_t)N * HID * 4);
  float* Bbuf   = (float*)alloc((size_t)N * HID * 4);
  float* Cbuf   = (float*)alloc((size_t)N * HID * 4);
  float* alphas = (float*)alloc((size_t)E * 8 * 4);
  int*   deg    = (int*)  alloc((size_t)N * 2 * 4);   // deg + cursor contiguous
  int*   cursor = deg + N;
  int*   offs   = (int*)  alloc((size_t)(N + 1) * 4);
  int*   csr_eid= (int*)  alloc((size_t)E * 4);
  int*   csr_src= (int*)  alloc((size_t)E * 4);

  // --- CSR by dst (reused by both GAT layers) ---
  hipMemsetAsync(deg, 0, (size_t)N * 2 * 4, stream);
  count_deg<<<(E + 255)/256, 256, 0, stream>>>(dstv, deg, E);
  scan_offsets<<<1, 1024, 0, stream>>>(deg, offs, N);
  fill_csr<<<(E + 255)/256, 256, 0, stream>>>(src, dstv, offs, cursor, csr_eid, csr_src, E);

  const dim3 gB(HID/64, (N + 63)/64);
  // h0 = elu(x @ W_in + b_in) -> A
  gemm_bias_act<2><<<gB, 256, 0, stream>>>(x, W_in, b_in, Abuf, N, 1024, 1024);

  for (int L = 0; L < 2; ++L){
    gemm_bias_act<0><<<gB, 256, 0, stream>>>(Abuf, g_Wl[L], g_bl[L], Bbuf, N, 1024, 1024); // xl
    gemm_bias_act<0><<<gB, 256, 0, stream>>>(Abuf, g_Wr[L], g_br[L], Cbuf, N, 1024, 1024); // xr
    edge_logits<<<(E + 3)/4, 256, 0, stream>>>(src, dstv, edge_attr, g_We[L], g_att[L], Bbuf, Cbuf, alphas, E);
    node_softmax<<<(N * HEADS + 255)/256, 256, 0, stream>>>(offs, csr_eid, alphas, N);
    aggregate<<<N, 256, 0, stream>>>(offs, csr_eid, csr_src, alphas, Bbuf, g_b[L], Abuf, N);
  }

  const dim3 g1(512/64, (N + 63)/64);
  gemm_bias_act<1><<<g1, 256, 0, stream>>>(Abuf, m1_W, m1_b, Bbuf, N, 1024, 512);
  const dim3 g2(128/64, (N + 63)/64);
  gemm_bias_act<1><<<g2, 256, 0, stream>>>(Bbuf, m2_W, m2_b, Cbuf, N, 512, 128);
  mlp_final<<<((size_t)N * 64 + 255)/256, 256, 0, stream>>>(Cbuf, m3_W, m3_b, out, N);
}

// Round 2
// 811.766 us; speedup vs baseline: 2.8218x; 2.8218x over previous
//
#include <hip/hip_runtime.h>
#include <math.h>

constexpr int HID = 1024;
constexpr float NEG_SLOPE = 0.2f;
constexpr float EPSV = 1e-16f;

typedef __bf16 bf16x8 __attribute__((ext_vector_type(8)));
typedef float f32x4 __attribute__((ext_vector_type(4)));
typedef unsigned short us8 __attribute__((ext_vector_type(8)));
typedef unsigned short us4 __attribute__((ext_vector_type(4)));
typedef unsigned short ushort_t;

__device__ __forceinline__ float4 ld4(const float* p){ return *reinterpret_cast<const float4*>(p); }
__device__ __forceinline__ float b2f(ushort_t u){ return __uint_as_float(((unsigned)u) << 16); }
__device__ __forceinline__ ushort_t f2b(float f){
  unsigned u = __float_as_uint(f);
  return (ushort_t)((u + 0x7FFFu + ((u >> 16) & 1u)) >> 16);
}

// ---------------- weight transpose + f32->bf16: WT[n*K+k] = bf16(W[k*N+n]) ----------------
__global__ __launch_bounds__(256) void transpose_f2b(const float* __restrict__ W, ushort_t* __restrict__ WT,
                                                     int K, int N){
  __shared__ float tile[32][33];
  const int tx = threadIdx.x & 31, ty = threadIdx.x >> 5;  // 32 x 8
  const int n0 = blockIdx.x * 32, k0 = blockIdx.y * 32;
  #pragma unroll
  for (int r = 0; r < 32; r += 8)
    tile[ty + r][tx] = W[(size_t)(k0 + ty + r) * N + n0 + tx];
  __syncthreads();
  #pragma unroll
  for (int r = 0; r < 32; r += 8)
    WT[(size_t)(n0 + ty + r) * K + k0 + tx] = f2b(tile[tx][ty + r]);
}

// ---------------- f32 -> bf16 elementwise ----------------
__global__ void convert_f2b(const float* __restrict__ in, ushort_t* __restrict__ out, size_t n){
  size_t i = ((size_t)blockIdx.x * blockDim.x + threadIdx.x) * 4;
  const size_t stride = (size_t)gridDim.x * blockDim.x * 4;
  for (; i < n; i += stride){
    const float4 v = ld4(in + i);
    us4 o = {f2b(v.x), f2b(v.y), f2b(v.z), f2b(v.w)};
    *reinterpret_cast<us4*>(out + i) = o;
  }
}

// ---------------- bf16 MFMA GEMM: C = act(A[M,K] @ BT[N,K]^T + bias), 128x128 tile, BK=64 ----------------
// ACT: 0 none, 1 relu, 2 elu.  OUTB: 1 -> write bf16 to Cb, else f32 to Cf.
template<int ACT, int OUTB>
__global__ __launch_bounds__(256, 2) void gemm_mfma(
    const ushort_t* __restrict__ A, const ushort_t* __restrict__ BT,
    const float* __restrict__ bias, float* __restrict__ Cf, ushort_t* __restrict__ Cb,
    int M, int K, int N)
{
  __shared__ __align__(16) ushort_t Asl[128 * 64];
  __shared__ __align__(16) ushort_t Bsl[128 * 64];
  const int tid = threadIdx.x;
  const int lane = tid & 63, wave = tid >> 6;
  const int wr = (wave >> 1) * 64, wc = (wave & 1) * 64;
  const int bm = blockIdx.y * 128, bn = blockIdx.x * 128;
  const int mrow = lane & 15;
  const int kof = (lane >> 4) * 8;

  f32x4 acc[4][4];
  #pragma unroll
  for (int i = 0; i < 4; ++i)
    #pragma unroll
    for (int j = 0; j < 4; ++j)
      acc[i][j] = (f32x4){0.f, 0.f, 0.f, 0.f};

  for (int k0 = 0; k0 < K; k0 += 64) {
    #pragma unroll
    for (int q = 0; q < 4; ++q) {
      const int c = q * 256 + tid;
      const int row = c >> 3, sl = (c & 7) * 8;
      int arow = bm + row; if (arow > M - 1) arow = M - 1;
      __builtin_amdgcn_global_load_lds(
        (const __attribute__((address_space(1))) unsigned int*)(A + (size_t)arow * K + k0 + sl),
        (__attribute__((address_space(3))) unsigned int*)(Asl + (size_t)(q * 256 + wave * 64) * 8),
        16, 0, 0);
      __builtin_amdgcn_global_load_lds(
        (const __attribute__((address_space(1))) unsigned int*)(BT + (size_t)(bn + row) * K + k0 + sl),
        (__attribute__((address_space(3))) unsigned int*)(Bsl + (size_t)(q * 256 + wave * 64) * 8),
        16, 0, 0);
    }
    __syncthreads();
    #pragma unroll
    for (int ks = 0; ks < 2; ++ks) {
      bf16x8 af[4], bfr[4];
      #pragma unroll
      for (int i = 0; i < 4; ++i)
        af[i] = *reinterpret_cast<const bf16x8*>(&Asl[(wr + i * 16 + mrow) * 64 + ks * 32 + kof]);
      #pragma unroll
      for (int j = 0; j < 4; ++j)
        bfr[j] = *reinterpret_cast<const bf16x8*>(&Bsl[(wc + j * 16 + mrow) * 64 + ks * 32 + kof]);
      #pragma unroll
      for (int i = 0; i < 4; ++i)
        #pragma unroll
        for (int j = 0; j < 4; ++j)
          acc[i][j] = __builtin_amdgcn_mfma_f32_16x16x32_bf16(af[i], bfr[j], acc[i][j], 0, 0, 0);
    }
    __syncthreads();
  }

  const int r0 = (lane >> 4) * 4;
  #pragma unroll
  for (int j = 0; j < 4; ++j) {
    const int col = bn + wc + j * 16 + mrow;
    const float bv = bias[col];
    #pragma unroll
    for (int i = 0; i < 4; ++i) {
      #pragma unroll
      for (int r = 0; r < 4; ++r) {
        const int row = bm + wr + i * 16 + r0 + r;
        if (row < M) {
          float t = acc[i][j][r] + bv;
          if (ACT == 1) t = fmaxf(t, 0.f);
          else if (ACT == 2) t = (t > 0.f) ? t : expm1f(t);
          if (OUTB) Cb[(size_t)row * N + col] = f2b(t);
          else      Cf[(size_t)row * N + col] = t;
        }
      }
    }
  }
}

// ---------------- CSR build ----------------
__global__ void count_deg(const int* __restrict__ dst, int* __restrict__ deg, int E){
  int e = blockIdx.x * blockDim.x + threadIdx.x;
  if (e < E) atomicAdd(&deg[dst[e]], 1);
}

__global__ __launch_bounds__(1024) void scan_offsets(const int* __restrict__ deg, int* __restrict__ offs, int n){
  __shared__ int sd[1024];
  const int tid = threadIdx.x;
  int running = 0;
  for (int base = 0; base < n; base += 1024){
    const int i = base + tid;
    const int v = (i < n) ? deg[i] : 0;
    sd[tid] = v;
    __syncthreads();
    for (int s = 1; s < 1024; s <<= 1){
      int t = (tid >= s) ? sd[tid - s] : 0;
      __syncthreads();
      sd[tid] += t;
      __syncthreads();
    }
    if (i < n) offs[i] = running + sd[tid] - v;
    running += sd[1023];
    __syncthreads();
  }
  if (tid == 0) offs[n] = running;
}

__global__ void fill_csr(const int* __restrict__ src, const int* __restrict__ dst,
                         const int* __restrict__ offs, int* __restrict__ cursor,
                         int* __restrict__ csr_eid, int* __restrict__ csr_src, int E){
  int e = blockIdx.x * blockDim.x + threadIdx.x;
  if (e < E){
    int d = dst[e];
    int pos = offs[d] + atomicAdd(&cursor[d], 1);
    csr_eid[pos] = e;
    csr_src[pos] = src[e];
  }
}

// ---------------- edge logits (bf16 xl/xr): one wave per edge ----------------
__global__ __launch_bounds__(256) void edge_logits_b(
    const int* __restrict__ src, const int* __restrict__ dst,
    const float* __restrict__ edge_attr, const float* __restrict__ We,
    const float* __restrict__ att, const ushort_t* __restrict__ xl,
    const ushort_t* __restrict__ xr, float* __restrict__ logits, int E)
{
  const int e = blockIdx.x * (blockDim.x >> 6) + (threadIdx.x >> 6);
  const int lane = threadIdx.x & 63;
  if (e >= E) return;
  const int s = src[e], d = dst[e];
  const float4 ea = ld4(&edge_attr[(size_t)e * 4]);
  float acc0 = 0.f, acc1 = 0.f;
  #pragma unroll
  for (int p = 0; p < 2; ++p){
    const int base = p * 512 + lane * 8;
    const us8 a8 = *reinterpret_cast<const us8*>(xl + (size_t)s * HID + base);
    const us8 b8 = *reinterpret_cast<const us8*>(xr + (size_t)d * HID + base);
    float sum = 0.f;
    #pragma unroll
    for (int j = 0; j < 8; ++j){
      const int dc = base + j;
      float v = b2f(a8[j]) + b2f(b8[j])
              + ea.x * We[dc] + ea.y * We[1024 + dc] + ea.z * We[2048 + dc] + ea.w * We[3072 + dc];
      v = (v > 0.f) ? v : NEG_SLOPE * v;
      sum += v * att[dc];
    }
    if (p == 0) acc0 = sum; else acc1 = sum;
  }
  #pragma unroll
  for (int m = 1; m <= 8; m <<= 1){
    acc0 += __shfl_xor(acc0, m, 64);
    acc1 += __shfl_xor(acc1, m, 64);
  }
  if ((lane & 15) == 0){
    logits[(size_t)e * 8 + (lane >> 4)]     = acc0;
    logits[(size_t)e * 8 + 4 + (lane >> 4)] = acc1;
  }
}

// ---------------- per-(node,head) softmax in place ----------------
__global__ void node_softmax(const int* __restrict__ offs, const int* __restrict__ csr_eid,
                             float* __restrict__ la, int N)
{
  const int idx = blockIdx.x * blockDim.x + threadIdx.x;
  if (idx >= N * 8) return;
  const int n = idx >> 3, h = idx & 7;
  const int o0 = offs[n], o1 = offs[n + 1];
  float mx = -INFINITY;
  for (int i = o0; i < o1; ++i) mx = fmaxf(mx, la[(size_t)csr_eid[i] * 8 + h]);
  const float lm = (o1 > o0) ? mx : 0.f;
  float ssum = 0.f;
  for (int i = o0; i < o1; ++i) ssum += expf(la[(size_t)csr_eid[i] * 8 + h] - lm);
  const float rd = 1.f / (ssum + EPSV);
  for (int i = o0; i < o1; ++i){
    const size_t p = (size_t)csr_eid[i] * 8 + h;
    la[p] = expf(la[p] - lm) * rd;
  }
}

// ---------------- aggregation: block per node; bf16 in, bf16 out (elu) ----------------
__global__ __launch_bounds__(256) void aggregate_b(
    const int* __restrict__ offs, const int* __restrict__ csr_eid, const int* __restrict__ csr_src,
    const float* __restrict__ alpha, const ushort_t* __restrict__ xl,
    const float* __restrict__ bias, ushort_t* __restrict__ out, int N)
{
  const int n = blockIdx.x;
  const int t = threadIdx.x;
  const int h = t >> 5;
  const int o0 = offs[n], o1 = offs[n + 1];
  float a0 = 0.f, a1 = 0.f, a2 = 0.f, a3 = 0.f;
  for (int i = o0; i < o1; ++i){
    const int eid = csr_eid[i], s = csr_src[i];
    const float al = alpha[(size_t)eid * 8 + h];
    const us4 v = *reinterpret_cast<const us4*>(xl + (size_t)s * HID + t * 4);
    a0 += b2f(v[0]) * al; a1 += b2f(v[1]) * al; a2 += b2f(v[2]) * al; a3 += b2f(v[3]) * al;
  }
  const float4 bb = ld4(&bias[t * 4]);
  float o[4] = {a0 + bb.x, a1 + bb.y, a2 + bb.z, a3 + bb.w};
  #pragma unroll
  for (int j = 0; j < 4; ++j) o[j] = (o[j] > 0.f) ? o[j] : expm1f(o[j]);
  us4 ov = {f2b(o[0]), f2b(o[1]), f2b(o[2]), f2b(o[3])};
  *reinterpret_cast<us4*>(out + (size_t)n * HID + t * 4) = ov;
}

// ---------------- final matvec + sigmoid: one wave per row ----------------
__global__ __launch_bounds__(256) void mlp_final(const float* __restrict__ h, const float* __restrict__ w,
                                                 const float* __restrict__ b, float* __restrict__ out, int M)
{
  const int row = (int)((blockIdx.x * (size_t)blockDim.x + threadIdx.x) >> 6);
  const int lane = threadIdx.x & 63;
  if (row >= M) return;
  const float2 v  = *reinterpret_cast<const float2*>(&h[(size_t)row * 128 + lane * 2]);
  const float2 ww = *reinterpret_cast<const float2*>(&w[lane * 2]);
  float s = v.x * ww.x + v.y * ww.y;
  #pragma unroll
  for (int m = 1; m <= 32; m <<= 1) s += __shfl_xor(s, m, 64);
  if (lane == 0) out[row] = 1.f / (1.f + expf(-(s + b[0])));
}

extern "C" void kernel_launch(void* const* d_in, const int* in_sizes, int n_in,
                              void* d_out, int out_size, void* d_ws, size_t ws_size,
                              hipStream_t stream)
{
  const float* x        = (const float*)d_in[0];
  const int*   ei       = (const int*)d_in[1];
  const float* edge_attr= (const float*)d_in[2];
  const float* W_in     = (const float*)d_in[3];
  const float* b_in     = (const float*)d_in[4];
  const float* m1_W     = (const float*)d_in[5];
  const float* m1_b     = (const float*)d_in[6];
  const float* m2_W     = (const float*)d_in[7];
  const float* m2_b     = (const float*)d_in[8];
  const float* m3_W     = (const float*)d_in[9];
  const float* m3_b     = (const float*)d_in[10];
  const float* g_Wl[2]  = {(const float*)d_in[11], (const float*)d_in[18]};
  const float* g_bl[2]  = {(const float*)d_in[12], (const float*)d_in[19]};
  const float* g_Wr[2]  = {(const float*)d_in[13], (const float*)d_in[20]};
  const float* g_br[2]  = {(const float*)d_in[14], (const float*)d_in[21]};
  const float* g_We[2]  = {(const float*)d_in[15], (const float*)d_in[22]};
  const float* g_att[2] = {(const float*)d_in[16], (const float*)d_in[23]};
  const float* g_b[2]   = {(const float*)d_in[17], (const float*)d_in[24]};

  const int Nn = in_sizes[0] / 1024;
  const int E  = in_sizes[1] / 2;
  const int* srcv = ei;
  const int* dstv = ei + E;
  float* out = (float*)d_out;

  char* wsp = (char*)d_ws;
  size_t off = 0;
  auto alloc = [&](size_t bytes)->char* {
    char* p = wsp + off;
    off = (off + bytes + 255) & ~(size_t)255;
    return p;
  };
  ushort_t* hbf  = (ushort_t*)alloc((size_t)Nn * HID * 2);
  ushort_t* ubuf = (ushort_t*)alloc((size_t)Nn * HID * 2);   // xbf, later m1 output
  ushort_t* xl   = (ushort_t*)alloc((size_t)Nn * HID * 2);
  ushort_t* xr   = (ushort_t*)alloc((size_t)Nn * HID * 2);
  float*    m2f  = (float*)   alloc((size_t)Nn * 128 * 4);
  float*  alphas = (float*)   alloc((size_t)E * 8 * 4);
  ushort_t* WinT = (ushort_t*)alloc((size_t)1024 * 1024 * 2);
  ushort_t* WlT0 = (ushort_t*)alloc((size_t)1024 * 1024 * 2);
  ushort_t* WrT0 = (ushort_t*)alloc((size_t)1024 * 1024 * 2);
  ushort_t* WlT1 = (ushort_t*)alloc((size_t)1024 * 1024 * 2);
  ushort_t* WrT1 = (ushort_t*)alloc((size_t)1024 * 1024 * 2);
  ushort_t* m1T  = (ushort_t*)alloc((size_t)512 * 1024 * 2);
  ushort_t* m2T  = (ushort_t*)alloc((size_t)128 * 512 * 2);
  int* deg    = (int*)alloc((size_t)Nn * 2 * 4);
  int* cursor = deg + Nn;
  int* offs   = (int*)alloc((size_t)(Nn + 1) * 4);
  int* csr_eid= (int*)alloc((size_t)E * 4);
  int* csr_src= (int*)alloc((size_t)E * 4);
  ushort_t* WlT[2] = {WlT0, WlT1};
  ushort_t* WrT[2] = {WrT0, WrT1};

  // --- weight transposes (f32 -> bf16 [N,K]) + input conversion ---
  transpose_f2b<<<dim3(32, 32), 256, 0, stream>>>(W_in, WinT, 1024, 1024);
  transpose_f2b<<<dim3(32, 32), 256, 0, stream>>>(g_Wl[0], WlT0, 1024, 1024);
  transpose_f2b<<<dim3(32, 32), 256, 0, stream>>>(g_Wr[0], WrT0, 1024, 1024);
  transpose_f2b<<<dim3(32, 32), 256, 0, stream>>>(g_Wl[1], WlT1, 1024, 1024);
  transpose_f2b<<<dim3(32, 32), 256, 0, stream>>>(g_Wr[1], WrT1, 1024, 1024);
  transpose_f2b<<<dim3(16, 32), 256, 0, stream>>>(m1_W, m1T, 1024, 512);
  transpose_f2b<<<dim3(4, 16), 256, 0, stream>>>(m2_W, m2T, 512, 128);
  convert_f2b<<<2048, 256, 0, stream>>>(x, ubuf, (size_t)Nn * HID);

  // --- CSR by dst ---
  hipMemsetAsync(deg, 0, (size_t)Nn * 2 * 4, stream);
  count_deg<<<(E + 255)/256, 256, 0, stream>>>(dstv, deg, E);
  scan_offsets<<<1, 1024, 0, stream>>>(deg, offs, Nn);
  fill_csr<<<(E + 255)/256, 256, 0, stream>>>(srcv, dstv, offs, cursor, csr_eid, csr_src, E);

  const int MB = (Nn + 127) / 128;
  // h0 = elu(x @ W_in + b_in) -> hbf (bf16)
  gemm_mfma<2, 1><<<dim3(8, MB), 256, 0, stream>>>(ubuf, WinT, b_in, nullptr, hbf, Nn, 1024, 1024);

  for (int L = 0; L < 2; ++L){
    gemm_mfma<0, 1><<<dim3(8, MB), 256, 0, stream>>>(hbf, WlT[L], g_bl[L], nullptr, xl, Nn, 1024, 1024);
    gemm_mfma<0, 1><<<dim3(8, MB), 256, 0, stream>>>(hbf, WrT[L], g_br[L], nullptr, xr, Nn, 1024, 1024);
    edge_logits_b<<<(E + 3)/4, 256, 0, stream>>>(srcv, dstv, edge_attr, g_We[L], g_att[L], xl, xr, alphas, E);
    node_softmax<<<(Nn * 8 + 255)/256, 256, 0, stream>>>(offs, csr_eid, alphas, Nn);
    aggregate_b<<<Nn, 256, 0, stream>>>(offs, csr_eid, csr_src, alphas, xl, g_b[L], hbf, Nn);
  }

  // MLP
  gemm_mfma<1, 1><<<dim3(4, MB), 256, 0, stream>>>(hbf, m1T, m1_b, nullptr, ubuf, Nn, 1024, 512);
  gemm_mfma<1, 0><<<dim3(1, MB), 256, 0, stream>>>(ubuf, m2T, m2_b, m2f, nullptr, Nn, 512, 128);
  mlp_final<<<((size_t)Nn * 64 + 255)/256, 256, 0, stream>>>(m2f, m3_W, m3_b, out, Nn);
}

// Round 3
// 632.281 us; speedup vs baseline: 3.6228x; 1.2839x over previous
//
#include <hip/hip_runtime.h>
#include <math.h>

constexpr int HID = 1024;
constexpr float NEG_SLOPE = 0.2f;
constexpr float EPSV = 1e-16f;

typedef __bf16 bf16x8 __attribute__((ext_vector_type(8)));
typedef float f32x4 __attribute__((ext_vector_type(4)));
typedef unsigned short us8 __attribute__((ext_vector_type(8)));
typedef unsigned short us4 __attribute__((ext_vector_type(4)));
typedef unsigned short ushort_t;

__device__ __forceinline__ float4 ld4(const float* p){ return *reinterpret_cast<const float4*>(p); }
__device__ __forceinline__ float b2f(ushort_t u){ return __uint_as_float(((unsigned)u) << 16); }
__device__ __forceinline__ ushort_t f2b(float f){
  unsigned u = __float_as_uint(f);
  return (ushort_t)((u + 0x7FFFu + ((u >> 16) & 1u)) >> 16);
}

// ---------------- weight transpose + f32->bf16: WT[n*K+k] = bf16(W[k*N+n]) ----------------
__global__ __launch_bounds__(256) void transpose_f2b(const float* __restrict__ W, ushort_t* __restrict__ WT,
                                                     int K, int N){
  __shared__ float tile[32][33];
  const int tx = threadIdx.x & 31, ty = threadIdx.x >> 5;  // 32 x 8
  const int n0 = blockIdx.x * 32, k0 = blockIdx.y * 32;
  #pragma unroll
  for (int r = 0; r < 32; r += 8)
    tile[ty + r][tx] = W[(size_t)(k0 + ty + r) * N + n0 + tx];
  __syncthreads();
  #pragma unroll
  for (int r = 0; r < 32; r += 8)
    WT[(size_t)(n0 + ty + r) * K + k0 + tx] = f2b(tile[tx][ty + r]);
}

// ---------------- f32 -> bf16 elementwise ----------------
__global__ void convert_f2b(const float* __restrict__ in, ushort_t* __restrict__ out, size_t n){
  size_t i = ((size_t)blockIdx.x * blockDim.x + threadIdx.x) * 4;
  const size_t stride = (size_t)gridDim.x * blockDim.x * 4;
  for (; i < n; i += stride){
    const float4 v = ld4(in + i);
    us4 o = {f2b(v.x), f2b(v.y), f2b(v.z), f2b(v.w)};
    *reinterpret_cast<us4*>(out + i) = o;
  }
}

// ---------------- bf16 MFMA GEMM: C = act(A[M,K] @ BT[N,K]^T + bias), 128x128 tile, BK=64 ----------------
template<int ACT, int OUTB>
__global__ __launch_bounds__(256, 2) void gemm_mfma(
    const ushort_t* __restrict__ A, const ushort_t* __restrict__ BT,
    const float* __restrict__ bias, float* __restrict__ Cf, ushort_t* __restrict__ Cb,
    int M, int K, int N)
{
  __shared__ __align__(16) ushort_t Asl[128 * 64];
  __shared__ __align__(16) ushort_t Bsl[128 * 64];
  const int tid = threadIdx.x;
  const int lane = tid & 63, wave = tid >> 6;
  const int wr = (wave >> 1) * 64, wc = (wave & 1) * 64;
  const int bm = blockIdx.y * 128, bn = blockIdx.x * 128;
  const int mrow = lane & 15;
  const int kof = (lane >> 4) * 8;

  f32x4 acc[4][4];
  #pragma unroll
  for (int i = 0; i < 4; ++i)
    #pragma unroll
    for (int j = 0; j < 4; ++j)
      acc[i][j] = (f32x4){0.f, 0.f, 0.f, 0.f};

  for (int k0 = 0; k0 < K; k0 += 64) {
    #pragma unroll
    for (int q = 0; q < 4; ++q) {
      const int c = q * 256 + tid;
      const int row = c >> 3, sl = (c & 7) * 8;
      int arow = bm + row; if (arow > M - 1) arow = M - 1;
      __builtin_amdgcn_global_load_lds(
        (const __attribute__((address_space(1))) unsigned int*)(A + (size_t)arow * K + k0 + sl),
        (__attribute__((address_space(3))) unsigned int*)(Asl + (size_t)(q * 256 + wave * 64) * 8),
        16, 0, 0);
      __builtin_amdgcn_global_load_lds(
        (const __attribute__((address_space(1))) unsigned int*)(BT + (size_t)(bn + row) * K + k0 + sl),
        (__attribute__((address_space(3))) unsigned int*)(Bsl + (size_t)(q * 256 + wave * 64) * 8),
        16, 0, 0);
    }
    __syncthreads();
    #pragma unroll
    for (int ks = 0; ks < 2; ++ks) {
      bf16x8 af[4], bfr[4];
      #pragma unroll
      for (int i = 0; i < 4; ++i)
        af[i] = *reinterpret_cast<const bf16x8*>(&Asl[(wr + i * 16 + mrow) * 64 + ks * 32 + kof]);
      #pragma unroll
      for (int j = 0; j < 4; ++j)
        bfr[j] = *reinterpret_cast<const bf16x8*>(&Bsl[(wc + j * 16 + mrow) * 64 + ks * 32 + kof]);
      #pragma unroll
      for (int i = 0; i < 4; ++i)
        #pragma unroll
        for (int j = 0; j < 4; ++j)
          acc[i][j] = __builtin_amdgcn_mfma_f32_16x16x32_bf16(af[i], bfr[j], acc[i][j], 0, 0, 0);
    }
    __syncthreads();
  }

  const int r0 = (lane >> 4) * 4;
  #pragma unroll
  for (int j = 0; j < 4; ++j) {
    const int col = bn + wc + j * 16 + mrow;
    const float bv = bias[col];
    #pragma unroll
    for (int i = 0; i < 4; ++i) {
      #pragma unroll
      for (int r = 0; r < 4; ++r) {
        const int row = bm + wr + i * 16 + r0 + r;
        if (row < M) {
          float t = acc[i][j][r] + bv;
          if (ACT == 1) t = fmaxf(t, 0.f);
          else if (ACT == 2) t = (t > 0.f) ? t : expm1f(t);
          if (OUTB) Cb[(size_t)row * N + col] = f2b(t);
          else      Cf[(size_t)row * N + col] = t;
        }
      }
    }
  }
}

// ---------------- CSR build ----------------
__global__ void count_deg(const int* __restrict__ dst, int* __restrict__ deg, int E){
  int e = blockIdx.x * blockDim.x + threadIdx.x;
  if (e < E) atomicAdd(&deg[dst[e]], 1);
}

__global__ __launch_bounds__(1024) void scan_offsets(const int* __restrict__ deg, int* __restrict__ offs, int n){
  __shared__ int sd[1024];
  const int tid = threadIdx.x;
  int running = 0;
  for (int base = 0; base < n; base += 1024){
    const int i = base + tid;
    const int v = (i < n) ? deg[i] : 0;
    sd[tid] = v;
    __syncthreads();
    for (int s = 1; s < 1024; s <<= 1){
      int t = (tid >= s) ? sd[tid - s] : 0;
      __syncthreads();
      sd[tid] += t;
      __syncthreads();
    }
    if (i < n) offs[i] = running + sd[tid] - v;
    running += sd[1023];
    __syncthreads();
  }
  if (tid == 0) offs[n] = running;
}

__global__ void fill_csr(const int* __restrict__ src, const int* __restrict__ dst,
                         const int* __restrict__ offs, int* __restrict__ cursor,
                         int* __restrict__ csr_eid, int* __restrict__ csr_src,
                         int* __restrict__ csr_dst, int E){
  int e = blockIdx.x * blockDim.x + threadIdx.x;
  if (e < E){
    int d = dst[e];
    int pos = offs[d] + atomicAdd(&cursor[d], 1);
    csr_eid[pos] = e;
    csr_src[pos] = src[e];
    csr_dst[pos] = d;
  }
}

// ---------------- edge logits over CSR order; We/att in registers; 2 edges/iter ----------------
// lane owns dims [lane*16, lane*16+16); head = lane>>3; logits written in POSITION order.
__global__ __launch_bounds__(256) void edge_logits_csr(
    const int* __restrict__ csr_src, const int* __restrict__ csr_dst, const int* __restrict__ csr_eid,
    const float* __restrict__ edge_attr, const float* __restrict__ We,
    const float* __restrict__ att, const ushort_t* __restrict__ xlr,
    float* __restrict__ logits, int E)
{
  const int lane = threadIdx.x & 63;
  const int wid  = blockIdx.x * (blockDim.x >> 6) + (threadIdx.x >> 6);
  const int nw   = gridDim.x * (blockDim.x >> 6);
  const int dimb = lane * 16;

  float wreg[4][16], areg[16];
  #pragma unroll
  for (int r = 0; r < 4; ++r)
    #pragma unroll
    for (int q = 0; q < 4; ++q){
      const float4 w4 = ld4(We + r * 1024 + dimb + q * 4);
      wreg[r][q*4+0] = w4.x; wreg[r][q*4+1] = w4.y; wreg[r][q*4+2] = w4.z; wreg[r][q*4+3] = w4.w;
    }
  #pragma unroll
  for (int q = 0; q < 4; ++q){
    const float4 a4 = ld4(att + dimb + q * 4);
    areg[q*4+0] = a4.x; areg[q*4+1] = a4.y; areg[q*4+2] = a4.z; areg[q*4+3] = a4.w;
  }

  for (int pos = wid * 2; pos < E; pos += nw * 2){
    const int posB = (pos + 1 < E) ? pos + 1 : pos;
    const int sA = csr_src[pos],  dA = csr_dst[pos],  eA = csr_eid[pos];
    const int sB = csr_src[posB], dB = csr_dst[posB], eB = csr_eid[posB];
    const us8* pA0 = reinterpret_cast<const us8*>(xlr + (size_t)sA * 2048 + dimb);
    const us8* pA1 = reinterpret_cast<const us8*>(xlr + (size_t)dA * 2048 + 1024 + dimb);
    const us8* pB0 = reinterpret_cast<const us8*>(xlr + (size_t)sB * 2048 + dimb);
    const us8* pB1 = reinterpret_cast<const us8*>(xlr + (size_t)dB * 2048 + 1024 + dimb);
    const us8 Al = pA0[0], Ah = pA0[1], Arl = pA1[0], Arh = pA1[1];
    const us8 Bl = pB0[0], Bh = pB0[1], Brl = pB1[0], Brh = pB1[1];
    const float4 eaA = ld4(edge_attr + (size_t)eA * 4);
    const float4 eaB = ld4(edge_attr + (size_t)eB * 4);

    float accA = 0.f, accB = 0.f;
    #pragma unroll
    for (int j = 0; j < 8; ++j){
      float v = b2f(Al[j]) + b2f(Arl[j])
              + eaA.x*wreg[0][j] + eaA.y*wreg[1][j] + eaA.z*wreg[2][j] + eaA.w*wreg[3][j];
      v = (v > 0.f) ? v : NEG_SLOPE * v;  accA += v * areg[j];
      float u = b2f(Bl[j]) + b2f(Brl[j])
              + eaB.x*wreg[0][j] + eaB.y*wreg[1][j] + eaB.z*wreg[2][j] + eaB.w*wreg[3][j];
      u = (u > 0.f) ? u : NEG_SLOPE * u;  accB += u * areg[j];
    }
    #pragma unroll
    for (int j = 0; j < 8; ++j){
      float v = b2f(Ah[j]) + b2f(Arh[j])
              + eaA.x*wreg[0][8+j] + eaA.y*wreg[1][8+j] + eaA.z*wreg[2][8+j] + eaA.w*wreg[3][8+j];
      v = (v > 0.f) ? v : NEG_SLOPE * v;  accA += v * areg[8+j];
      float u = b2f(Bh[j]) + b2f(Brh[j])
              + eaB.x*wreg[0][8+j] + eaB.y*wreg[1][8+j] + eaB.z*wreg[2][8+j] + eaB.w*wreg[3][8+j];
      u = (u > 0.f) ? u : NEG_SLOPE * u;  accB += u * areg[8+j];
    }
    #pragma unroll
    for (int m = 1; m <= 4; m <<= 1){
      accA += __shfl_xor(accA, m, 64);
      accB += __shfl_xor(accB, m, 64);
    }
    if ((lane & 7) == 0){
      logits[(size_t)pos  * 8 + (lane >> 3)] = accA;
      logits[(size_t)posB * 8 + (lane >> 3)] = accB;
    }
  }
}

// ---------------- per-(node,head) softmax in place (position-ordered logits) ----------------
__global__ void node_softmax(const int* __restrict__ offs, float* __restrict__ la, int N)
{
  const int idx = blockIdx.x * blockDim.x + threadIdx.x;
  if (idx >= N * 8) return;
  const int n = idx >> 3, h = idx & 7;
  const int o0 = offs[n], o1 = offs[n + 1];
  float mx = -INFINITY;
  for (int i = o0; i < o1; ++i) mx = fmaxf(mx, la[(size_t)i * 8 + h]);
  const float lm = (o1 > o0) ? mx : 0.f;
  float ssum = 0.f;
  for (int i = o0; i < o1; ++i) ssum += expf(la[(size_t)i * 8 + h] - lm);
  const float rd = 1.f / (ssum + EPSV);
  for (int i = o0; i < o1; ++i){
    const size_t p = (size_t)i * 8 + h;
    la[p] = expf(la[p] - lm) * rd;
  }
}

// ---------------- aggregation: block per node; alpha position-ordered; xl = xlr[:, 0:1024] ----------------
__global__ __launch_bounds__(256) void aggregate_b(
    const int* __restrict__ offs, const int* __restrict__ csr_src,
    const float* __restrict__ alpha, const ushort_t* __restrict__ xlr,
    const float* __restrict__ bias, ushort_t* __restrict__ out, int N)
{
  const int n = blockIdx.x;
  const int t = threadIdx.x;
  const int h = t >> 5;
  const int o0 = offs[n], o1 = offs[n + 1];
  float a0 = 0.f, a1 = 0.f, a2 = 0.f, a3 = 0.f;
  for (int i = o0; i < o1; ++i){
    const int s = csr_src[i];
    const float al = alpha[(size_t)i * 8 + h];
    const us4 v = *reinterpret_cast<const us4*>(xlr + (size_t)s * 2048 + t * 4);
    a0 += b2f(v[0]) * al; a1 += b2f(v[1]) * al; a2 += b2f(v[2]) * al; a3 += b2f(v[3]) * al;
  }
  const float4 bb = ld4(&bias[t * 4]);
  float o[4] = {a0 + bb.x, a1 + bb.y, a2 + bb.z, a3 + bb.w};
  #pragma unroll
  for (int j = 0; j < 4; ++j) o[j] = (o[j] > 0.f) ? o[j] : expm1f(o[j]);
  us4 ov = {f2b(o[0]), f2b(o[1]), f2b(o[2]), f2b(o[3])};
  *reinterpret_cast<us4*>(out + (size_t)n * HID + t * 4) = ov;
}

// ---------------- final matvec + sigmoid: one wave per row ----------------
__global__ __launch_bounds__(256) void mlp_final(const float* __restrict__ h, const float* __restrict__ w,
                                                 const float* __restrict__ b, float* __restrict__ out, int M)
{
  const int row = (int)((blockIdx.x * (size_t)blockDim.x + threadIdx.x) >> 6);
  const int lane = threadIdx.x & 63;
  if (row >= M) return;
  const float2 v  = *reinterpret_cast<const float2*>(&h[(size_t)row * 128 + lane * 2]);
  const float2 ww = *reinterpret_cast<const float2*>(&w[lane * 2]);
  float s = v.x * ww.x + v.y * ww.y;
  #pragma unroll
  for (int m = 1; m <= 32; m <<= 1) s += __shfl_xor(s, m, 64);
  if (lane == 0) out[row] = 1.f / (1.f + expf(-(s + b[0])));
}

extern "C" void kernel_launch(void* const* d_in, const int* in_sizes, int n_in,
                              void* d_out, int out_size, void* d_ws, size_t ws_size,
                              hipStream_t stream)
{
  const float* x        = (const float*)d_in[0];
  const int*   ei       = (const int*)d_in[1];
  const float* edge_attr= (const float*)d_in[2];
  const float* W_in     = (const float*)d_in[3];
  const float* b_in     = (const float*)d_in[4];
  const float* m1_W     = (const float*)d_in[5];
  const float* m1_b     = (const float*)d_in[6];
  const float* m2_W     = (const float*)d_in[7];
  const float* m2_b     = (const float*)d_in[8];
  const float* m3_W     = (const float*)d_in[9];
  const float* m3_b     = (const float*)d_in[10];
  const float* g_Wl[2]  = {(const float*)d_in[11], (const float*)d_in[18]};
  const float* g_bl[2]  = {(const float*)d_in[12], (const float*)d_in[19]};
  const float* g_Wr[2]  = {(const float*)d_in[13], (const float*)d_in[20]};
  const float* g_br[2]  = {(const float*)d_in[14], (const float*)d_in[21]};
  const float* g_We[2]  = {(const float*)d_in[15], (const float*)d_in[22]};
  const float* g_att[2] = {(const float*)d_in[16], (const float*)d_in[23]};
  const float* g_b[2]   = {(const float*)d_in[17], (const float*)d_in[24]};

  const int Nn = in_sizes[0] / 1024;
  const int E  = in_sizes[1] / 2;
  const int* srcv = ei;
  const int* dstv = ei + E;
  float* out = (float*)d_out;

  char* wsp = (char*)d_ws;
  size_t off = 0;
  auto alloc = [&](size_t bytes)->char* {
    char* p = wsp + off;
    off = (off + bytes + 255) & ~(size_t)255;
    return p;
  };
  ushort_t* hbf  = (ushort_t*)alloc((size_t)Nn * HID * 2);
  ushort_t* ubuf = (ushort_t*)alloc((size_t)Nn * HID * 2);       // x bf16, later m1 output
  ushort_t* xlr  = (ushort_t*)alloc((size_t)Nn * 2048 * 2);      // [xl | xr]
  float*    m2f  = (float*)   alloc((size_t)Nn * 128 * 4);
  float*  alphas = (float*)   alloc((size_t)E * 8 * 4);
  ushort_t* WinT = (ushort_t*)alloc((size_t)1024 * 1024 * 2);
  ushort_t* Wlr0 = (ushort_t*)alloc((size_t)2048 * 1024 * 2);
  ushort_t* Wlr1 = (ushort_t*)alloc((size_t)2048 * 1024 * 2);
  ushort_t* m1T  = (ushort_t*)alloc((size_t)512 * 1024 * 2);
  ushort_t* m2T  = (ushort_t*)alloc((size_t)128 * 512 * 2);
  float*  biasc  = (float*)   alloc((size_t)2048 * 2 * 4);       // concat biases, both layers
  int* deg    = (int*)alloc((size_t)Nn * 2 * 4);
  int* cursor = deg + Nn;
  int* offs   = (int*)alloc((size_t)(Nn + 1) * 4);
  int* csr_eid= (int*)alloc((size_t)E * 4);
  int* csr_src= (int*)alloc((size_t)E * 4);
  int* csr_dst= (int*)alloc((size_t)E * 4);
  ushort_t* Wlr[2]  = {Wlr0, Wlr1};
  float*    blr[2]  = {biasc, biasc + 2048};

  // --- weight prep: transposed bf16, Wl/Wr merged; concat biases (d2d copies) ---
  transpose_f2b<<<dim3(32, 32), 256, 0, stream>>>(W_in, WinT, 1024, 1024);
  transpose_f2b<<<dim3(32, 32), 256, 0, stream>>>(g_Wl[0], Wlr0,              1024, 1024);
  transpose_f2b<<<dim3(32, 32), 256, 0, stream>>>(g_Wr[0], Wlr0 + 1024*1024,  1024, 1024);
  transpose_f2b<<<dim3(32, 32), 256, 0, stream>>>(g_Wl[1], Wlr1,              1024, 1024);
  transpose_f2b<<<dim3(32, 32), 256, 0, stream>>>(g_Wr[1], Wlr1 + 1024*1024,  1024, 1024);
  transpose_f2b<<<dim3(16, 32), 256, 0, stream>>>(m1_W, m1T, 1024, 512);
  transpose_f2b<<<dim3(4, 16), 256, 0, stream>>>(m2_W, m2T, 512, 128);
  convert_f2b<<<2048, 256, 0, stream>>>(x, ubuf, (size_t)Nn * HID);
  hipMemcpyAsync(biasc,        g_bl[0], 1024*4, hipMemcpyDeviceToDevice, stream);
  hipMemcpyAsync(biasc + 1024, g_br[0], 1024*4, hipMemcpyDeviceToDevice, stream);
  hipMemcpyAsync(biasc + 2048, g_bl[1], 1024*4, hipMemcpyDeviceToDevice, stream);
  hipMemcpyAsync(biasc + 3072, g_br[1], 1024*4, hipMemcpyDeviceToDevice, stream);

  // --- CSR by dst ---
  hipMemsetAsync(deg, 0, (size_t)Nn * 2 * 4, stream);
  count_deg<<<(E + 255)/256, 256, 0, stream>>>(dstv, deg, E);
  scan_offsets<<<1, 1024, 0, stream>>>(deg, offs, Nn);
  fill_csr<<<(E + 255)/256, 256, 0, stream>>>(srcv, dstv, offs, cursor, csr_eid, csr_src, csr_dst, E);

  const int MB = (Nn + 127) / 128;
  // h0 = elu(x @ W_in + b_in) -> hbf (bf16)
  gemm_mfma<2, 1><<<dim3(8, MB), 256, 0, stream>>>(ubuf, WinT, b_in, nullptr, hbf, Nn, 1024, 1024);

  for (int L = 0; L < 2; ++L){
    gemm_mfma<0, 1><<<dim3(16, MB), 256, 0, stream>>>(hbf, Wlr[L], blr[L], nullptr, xlr, Nn, 1024, 2048);
    edge_logits_csr<<<1024, 256, 0, stream>>>(csr_src, csr_dst, csr_eid, edge_attr, g_We[L], g_att[L], xlr, alphas, E);
    node_softmax<<<(Nn * 8 + 255)/256, 256, 0, stream>>>(offs, alphas, Nn);
    aggregate_b<<<Nn, 256, 0, stream>>>(offs, csr_src, alphas, xlr, g_b[L], hbf, Nn);
  }

  // MLP
  gemm_mfma<1, 1><<<dim3(4, MB), 256, 0, stream>>>(hbf, m1T, m1_b, nullptr, ubuf, Nn, 1024, 512);
  gemm_mfma<1, 0><<<dim3(1, MB), 256, 0, stream>>>(ubuf, m2T, m2_b, m2f, nullptr, Nn, 512, 128);
  mlp_final<<<((size_t)Nn * 64 + 255)/256, 256, 0, stream>>>(m2f, m3_W, m3_b, out, Nn);
}

// Round 4
// 514.863 us; speedup vs baseline: 4.4490x; 1.2281x over previous
//
#include <hip/hip_runtime.h>
#include <math.h>

constexpr int HID = 1024;
constexpr float NEG_SLOPE = 0.2f;
constexpr float EPSV = 1e-16f;

typedef __bf16 bf16x8 __attribute__((ext_vector_type(8)));
typedef float f32x4 __attribute__((ext_vector_type(4)));
typedef unsigned short us4 __attribute__((ext_vector_type(4)));
typedef unsigned short ushort_t;

__device__ __forceinline__ float4 ld4(const float* p){ return *reinterpret_cast<const float4*>(p); }
__device__ __forceinline__ float b2f(ushort_t u){ return __uint_as_float(((unsigned)u) << 16); }
__device__ __forceinline__ ushort_t f2b(float f){
  unsigned u = __float_as_uint(f);
  return (ushort_t)((u + 0x7FFFu + ((u >> 16) & 1u)) >> 16);
}

// ---------------- weight transpose + f32->bf16: WT[n*K+k] = bf16(W[k*N+n]) ----------------
__global__ __launch_bounds__(256) void transpose_f2b(const float* __restrict__ W, ushort_t* __restrict__ WT,
                                                     int K, int N){
  __shared__ float tile[32][33];
  const int tx = threadIdx.x & 31, ty = threadIdx.x >> 5;  // 32 x 8
  const int n0 = blockIdx.x * 32, k0 = blockIdx.y * 32;
  #pragma unroll
  for (int r = 0; r < 32; r += 8)
    tile[ty + r][tx] = W[(size_t)(k0 + ty + r) * N + n0 + tx];
  __syncthreads();
  #pragma unroll
  for (int r = 0; r < 32; r += 8)
    WT[(size_t)(n0 + ty + r) * K + k0 + tx] = f2b(tile[tx][ty + r]);
}

// ---------------- f32 -> bf16 elementwise ----------------
__global__ void convert_f2b(const float* __restrict__ in, ushort_t* __restrict__ out, size_t n){
  size_t i = ((size_t)blockIdx.x * blockDim.x + threadIdx.x) * 4;
  const size_t stride = (size_t)gridDim.x * blockDim.x * 4;
  for (; i < n; i += stride){
    const float4 v = ld4(in + i);
    us4 o = {f2b(v.x), f2b(v.y), f2b(v.z), f2b(v.w)};
    *reinterpret_cast<us4*>(out + i) = o;
  }
}

// ---------------- bf16 MFMA GEMM: C = act(A[M,K] @ BT[N,K]^T + bias), 128x128 tile, BK=64 ----------------
template<int ACT, int OUTB>
__global__ __launch_bounds__(256, 2) void gemm_mfma(
    const ushort_t* __restrict__ A, const ushort_t* __restrict__ BT,
    const float* __restrict__ bias, float* __restrict__ Cf, ushort_t* __restrict__ Cb,
    int M, int K, int N)
{
  __shared__ __align__(16) ushort_t Asl[128 * 64];
  __shared__ __align__(16) ushort_t Bsl[128 * 64];
  const int tid = threadIdx.x;
  const int lane = tid & 63, wave = tid >> 6;
  const int wr = (wave >> 1) * 64, wc = (wave & 1) * 64;
  const int bm = blockIdx.y * 128, bn = blockIdx.x * 128;
  const int mrow = lane & 15;
  const int kof = (lane >> 4) * 8;

  f32x4 acc[4][4];
  #pragma unroll
  for (int i = 0; i < 4; ++i)
    #pragma unroll
    for (int j = 0; j < 4; ++j)
      acc[i][j] = (f32x4){0.f, 0.f, 0.f, 0.f};

  for (int k0 = 0; k0 < K; k0 += 64) {
    #pragma unroll
    for (int q = 0; q < 4; ++q) {
      const int c = q * 256 + tid;
      const int row = c >> 3, sl = (c & 7) * 8;
      int arow = bm + row; if (arow > M - 1) arow = M - 1;
      __builtin_amdgcn_global_load_lds(
        (const __attribute__((address_space(1))) unsigned int*)(A + (size_t)arow * K + k0 + sl),
        (__attribute__((address_space(3))) unsigned int*)(Asl + (size_t)(q * 256 + wave * 64) * 8),
        16, 0, 0);
      __builtin_amdgcn_global_load_lds(
        (const __attribute__((address_space(1))) unsigned int*)(BT + (size_t)(bn + row) * K + k0 + sl),
        (__attribute__((address_space(3))) unsigned int*)(Bsl + (size_t)(q * 256 + wave * 64) * 8),
        16, 0, 0);
    }
    __syncthreads();
    #pragma unroll
    for (int ks = 0; ks < 2; ++ks) {
      bf16x8 af[4], bfr[4];
      #pragma unroll
      for (int i = 0; i < 4; ++i)
        af[i] = *reinterpret_cast<const bf16x8*>(&Asl[(wr + i * 16 + mrow) * 64 + ks * 32 + kof]);
      #pragma unroll
      for (int j = 0; j < 4; ++j)
        bfr[j] = *reinterpret_cast<const bf16x8*>(&Bsl[(wc + j * 16 + mrow) * 64 + ks * 32 + kof]);
      #pragma unroll
      for (int i = 0; i < 4; ++i)
        #pragma unroll
        for (int j = 0; j < 4; ++j)
          acc[i][j] = __builtin_amdgcn_mfma_f32_16x16x32_bf16(af[i], bfr[j], acc[i][j], 0, 0, 0);
    }
    __syncthreads();
  }

  const int r0 = (lane >> 4) * 4;
  #pragma unroll
  for (int j = 0; j < 4; ++j) {
    const int col = bn + wc + j * 16 + mrow;
    const float bv = bias[col];
    #pragma unroll
    for (int i = 0; i < 4; ++i) {
      #pragma unroll
      for (int r = 0; r < 4; ++r) {
        const int row = bm + wr + i * 16 + r0 + r;
        if (row < M) {
          float t = acc[i][j][r] + bv;
          if (ACT == 1) t = fmaxf(t, 0.f);
          else if (ACT == 2) t = (t > 0.f) ? t : expm1f(t);
          if (OUTB) Cb[(size_t)row * N + col] = f2b(t);
          else      Cf[(size_t)row * N + col] = t;
        }
      }
    }
  }
}

// ---------------- CSR build ----------------
__global__ void count_deg(const int* __restrict__ dst, int* __restrict__ deg, int E){
  int e = blockIdx.x * blockDim.x + threadIdx.x;
  if (e < E) atomicAdd(&deg[dst[e]], 1);
}

__global__ __launch_bounds__(1024) void scan_offsets(const int* __restrict__ deg, int* __restrict__ offs, int n){
  __shared__ int sd[1024];
  const int tid = threadIdx.x;
  int running = 0;
  for (int base = 0; base < n; base += 1024){
    const int i = base + tid;
    const int v = (i < n) ? deg[i] : 0;
    sd[tid] = v;
    __syncthreads();
    for (int s = 1; s < 1024; s <<= 1){
      int t = (tid >= s) ? sd[tid - s] : 0;
      __syncthreads();
      sd[tid] += t;
      __syncthreads();
    }
    if (i < n) offs[i] = running + sd[tid] - v;
    running += sd[1023];
    __syncthreads();
  }
  if (tid == 0) offs[n] = running;
}

__global__ void fill_csr(const int* __restrict__ src, const int* __restrict__ dst,
                         const int* __restrict__ offs, int* __restrict__ cursor,
                         int* __restrict__ csr_eid, int* __restrict__ csr_src, int E){
  int e = blockIdx.x * blockDim.x + threadIdx.x;
  if (e < E){
    int d = dst[e];
    int pos = offs[d] + atomicAdd(&cursor[d], 1);
    csr_eid[pos] = e;
    csr_src[pos] = src[e];
  }
}

// ---------------- fused GATv2: logits + online softmax + aggregate + bias + elu ----------------
// One block (256 thr) per dst node. Thread t owns dims [4t, 4t+4); head = t>>5.
// out[n] = elu( sum_i alpha_i * xl[src_i] + bias ), alpha from online softmax over in-edges.
__global__ __launch_bounds__(256) void fused_gat(
    const int* __restrict__ offs, const int* __restrict__ csr_src, const int* __restrict__ csr_eid,
    const float* __restrict__ edge_attr, const float* __restrict__ We, const float* __restrict__ att,
    const ushort_t* __restrict__ xlr, const float* __restrict__ bias,
    ushort_t* __restrict__ out, int N)
{
  const int n = blockIdx.x;
  const int t = threadIdx.x;
  const int d0 = t * 4;

  // per-thread constants in registers
  const float4 W0 = ld4(We + d0);
  const float4 W1 = ld4(We + 1024 + d0);
  const float4 W2 = ld4(We + 2048 + d0);
  const float4 W3 = ld4(We + 3072 + d0);
  const float4 AT = ld4(att + d0);
  const us4 xrv = *reinterpret_cast<const us4*>(xlr + (size_t)n * 2048 + 1024 + d0);
  const float xr0 = b2f(xrv[0]), xr1 = b2f(xrv[1]), xr2 = b2f(xrv[2]), xr3 = b2f(xrv[3]);

  const int o0 = offs[n], o1 = offs[n + 1];

  float acc0 = 0.f, acc1 = 0.f, acc2 = 0.f, acc3 = 0.f;
  float lsum = 0.f, mcur = -INFINITY;

  us4 xv = {0,0,0,0};
  float4 ea = make_float4(0.f,0.f,0.f,0.f);
  if (o0 < o1){
    const int s = csr_src[o0], e = csr_eid[o0];
    xv = *reinterpret_cast<const us4*>(xlr + (size_t)s * 2048 + d0);
    ea = ld4(edge_attr + (size_t)e * 4);
  }

  for (int i = o0; i < o1; ++i){
    const us4 xc = xv;
    const float4 eac = ea;
    if (i + 1 < o1){
      const int s = csr_src[i + 1], e = csr_eid[i + 1];
      xv = *reinterpret_cast<const us4*>(xlr + (size_t)s * 2048 + d0);
      ea = ld4(edge_attr + (size_t)e * 4);
    }
    const float xf0 = b2f(xc[0]), xf1 = b2f(xc[1]), xf2 = b2f(xc[2]), xf3 = b2f(xc[3]);
    float m0 = xf0 + xr0 + eac.x*W0.x + eac.y*W1.x + eac.z*W2.x + eac.w*W3.x;
    float m1 = xf1 + xr1 + eac.x*W0.y + eac.y*W1.y + eac.z*W2.y + eac.w*W3.y;
    float m2 = xf2 + xr2 + eac.x*W0.z + eac.y*W1.z + eac.z*W2.z + eac.w*W3.z;
    float m3 = xf3 + xr3 + eac.x*W0.w + eac.y*W1.w + eac.z*W2.w + eac.w*W3.w;
    m0 = (m0 > 0.f) ? m0 : NEG_SLOPE * m0;
    m1 = (m1 > 0.f) ? m1 : NEG_SLOPE * m1;
    m2 = (m2 > 0.f) ? m2 : NEG_SLOPE * m2;
    m3 = (m3 > 0.f) ? m3 : NEG_SLOPE * m3;
    float z = m0*AT.x + m1*AT.y + m2*AT.z + m3*AT.w;
    #pragma unroll
    for (int sh = 1; sh <= 16; sh <<= 1) z += __shfl_xor(z, sh, 64);   // 32-lane (head) sum

    // online softmax update (uniform across the 32-lane head group)
    const float mn = fmaxf(mcur, z);
    const float sc = expf(mcur - mn);   // first iter: exp(-inf) = 0
    const float p  = expf(z - mn);
    lsum = lsum * sc + p;
    acc0 = acc0 * sc + p * xf0;
    acc1 = acc1 * sc + p * xf1;
    acc2 = acc2 * sc + p * xf2;
    acc3 = acc3 * sc + p * xf3;
    mcur = mn;
  }

  const float r = 1.f / (lsum + EPSV);
  const float4 BV = ld4(bias + d0);
  float o0v = acc0 * r + BV.x;
  float o1v = acc1 * r + BV.y;
  float o2v = acc2 * r + BV.z;
  float o3v = acc3 * r + BV.w;
  o0v = (o0v > 0.f) ? o0v : expm1f(o0v);
  o1v = (o1v > 0.f) ? o1v : expm1f(o1v);
  o2v = (o2v > 0.f) ? o2v : expm1f(o2v);
  o3v = (o3v > 0.f) ? o3v : expm1f(o3v);
  us4 ov = {f2b(o0v), f2b(o1v), f2b(o2v), f2b(o3v)};
  *reinterpret_cast<us4*>(out + (size_t)n * HID + d0) = ov;
}

// ---------------- final matvec + sigmoid: one wave per row ----------------
__global__ __launch_bounds__(256) void mlp_final(const float* __restrict__ h, const float* __restrict__ w,
                                                 const float* __restrict__ b, float* __restrict__ out, int M)
{
  const int row = (int)((blockIdx.x * (size_t)blockDim.x + threadIdx.x) >> 6);
  const int lane = threadIdx.x & 63;
  if (row >= M) return;
  const float2 v  = *reinterpret_cast<const float2*>(&h[(size_t)row * 128 + lane * 2]);
  const float2 ww = *reinterpret_cast<const float2*>(&w[lane * 2]);
  float s = v.x * ww.x + v.y * ww.y;
  #pragma unroll
  for (int m = 1; m <= 32; m <<= 1) s += __shfl_xor(s, m, 64);
  if (lane == 0) out[row] = 1.f / (1.f + expf(-(s + b[0])));
}

extern "C" void kernel_launch(void* const* d_in, const int* in_sizes, int n_in,
                              void* d_out, int out_size, void* d_ws, size_t ws_size,
                              hipStream_t stream)
{
  const float* x        = (const float*)d_in[0];
  const int*   ei       = (const int*)d_in[1];
  const float* edge_attr= (const float*)d_in[2];
  const float* W_in     = (const float*)d_in[3];
  const float* b_in     = (const float*)d_in[4];
  const float* m1_W     = (const float*)d_in[5];
  const float* m1_b     = (const float*)d_in[6];
  const float* m2_W     = (const float*)d_in[7];
  const float* m2_b     = (const float*)d_in[8];
  const float* m3_W     = (const float*)d_in[9];
  const float* m3_b     = (const float*)d_in[10];
  const float* g_Wl[2]  = {(const float*)d_in[11], (const float*)d_in[18]};
  const float* g_bl[2]  = {(const float*)d_in[12], (const float*)d_in[19]};
  const float* g_Wr[2]  = {(const float*)d_in[13], (const float*)d_in[20]};
  const float* g_br[2]  = {(const float*)d_in[14], (const float*)d_in[21]};
  const float* g_We[2]  = {(const float*)d_in[15], (const float*)d_in[22]};
  const float* g_att[2] = {(const float*)d_in[16], (const float*)d_in[23]};
  const float* g_b[2]   = {(const float*)d_in[17], (const float*)d_in[24]};

  const int Nn = in_sizes[0] / 1024;
  const int E  = in_sizes[1] / 2;
  const int* srcv = ei;
  const int* dstv = ei + E;
  float* out = (float*)d_out;

  char* wsp = (char*)d_ws;
  size_t off = 0;
  auto alloc = [&](size_t bytes)->char* {
    char* p = wsp + off;
    off = (off + bytes + 255) & ~(size_t)255;
    return p;
  };
  ushort_t* hbf  = (ushort_t*)alloc((size_t)Nn * HID * 2);
  ushort_t* ubuf = (ushort_t*)alloc((size_t)Nn * HID * 2);       // x bf16, later m1 output
  ushort_t* xlr  = (ushort_t*)alloc((size_t)Nn * 2048 * 2);      // [xl | xr]
  float*    m2f  = (float*)   alloc((size_t)Nn * 128 * 4);
  ushort_t* WinT = (ushort_t*)alloc((size_t)1024 * 1024 * 2);
  ushort_t* Wlr0 = (ushort_t*)alloc((size_t)2048 * 1024 * 2);
  ushort_t* Wlr1 = (ushort_t*)alloc((size_t)2048 * 1024 * 2);
  ushort_t* m1T  = (ushort_t*)alloc((size_t)512 * 1024 * 2);
  ushort_t* m2T  = (ushort_t*)alloc((size_t)128 * 512 * 2);
  float*  biasc  = (float*)   alloc((size_t)2048 * 2 * 4);       // concat biases, both layers
  int* deg    = (int*)alloc((size_t)Nn * 2 * 4);
  int* cursor = deg + Nn;
  int* offs   = (int*)alloc((size_t)(Nn + 1) * 4);
  int* csr_eid= (int*)alloc((size_t)E * 4);
  int* csr_src= (int*)alloc((size_t)E * 4);
  ushort_t* Wlr[2]  = {Wlr0, Wlr1};
  float*    blr[2]  = {biasc, biasc + 2048};

  // --- weight prep: transposed bf16, Wl/Wr merged; concat biases (d2d copies) ---
  transpose_f2b<<<dim3(32, 32), 256, 0, stream>>>(W_in, WinT, 1024, 1024);
  transpose_f2b<<<dim3(32, 32), 256, 0, stream>>>(g_Wl[0], Wlr0,              1024, 1024);
  transpose_f2b<<<dim3(32, 32), 256, 0, stream>>>(g_Wr[0], Wlr0 + 1024*1024,  1024, 1024);
  transpose_f2b<<<dim3(32, 32), 256, 0, stream>>>(g_Wl[1], Wlr1,              1024, 1024);
  transpose_f2b<<<dim3(32, 32), 256, 0, stream>>>(g_Wr[1], Wlr1 + 1024*1024,  1024, 1024);
  transpose_f2b<<<dim3(16, 32), 256, 0, stream>>>(m1_W, m1T, 1024, 512);
  transpose_f2b<<<dim3(4, 16), 256, 0, stream>>>(m2_W, m2T, 512, 128);
  convert_f2b<<<2048, 256, 0, stream>>>(x, ubuf, (size_t)Nn * HID);
  hipMemcpyAsync(biasc,        g_bl[0], 1024*4, hipMemcpyDeviceToDevice, stream);
  hipMemcpyAsync(biasc + 1024, g_br[0], 1024*4, hipMemcpyDeviceToDevice, stream);
  hipMemcpyAsync(biasc + 2048, g_bl[1], 1024*4, hipMemcpyDeviceToDevice, stream);
  hipMemcpyAsync(biasc + 3072, g_br[1], 1024*4, hipMemcpyDeviceToDevice, stream);

  // --- CSR by dst ---
  hipMemsetAsync(deg, 0, (size_t)Nn * 2 * 4, stream);
  count_deg<<<(E + 255)/256, 256, 0, stream>>>(dstv, deg, E);
  scan_offsets<<<1, 1024, 0, stream>>>(deg, offs, Nn);
  fill_csr<<<(E + 255)/256, 256, 0, stream>>>(srcv, dstv, offs, cursor, csr_eid, csr_src, E);

  const int MB = (Nn + 127) / 128;
  // h0 = elu(x @ W_in + b_in) -> hbf (bf16)
  gemm_mfma<2, 1><<<dim3(8, MB), 256, 0, stream>>>(ubuf, WinT, b_in, nullptr, hbf, Nn, 1024, 1024);

  for (int L = 0; L < 2; ++L){
    gemm_mfma<0, 1><<<dim3(16, MB), 256, 0, stream>>>(hbf, Wlr[L], blr[L], nullptr, xlr, Nn, 1024, 2048);
    fused_gat<<<Nn, 256, 0, stream>>>(offs, csr_src, csr_eid, edge_attr, g_We[L], g_att[L], xlr, g_b[L], hbf, Nn);
  }

  // MLP
  gemm_mfma<1, 1><<<dim3(4, MB), 256, 0, stream>>>(hbf, m1T, m1_b, nullptr, ubuf, Nn, 1024, 512);
  gemm_mfma<1, 0><<<dim3(1, MB), 256, 0, stream>>>(ubuf, m2T, m2_b, m2f, nullptr, Nn, 512, 128);
  mlp_final<<<((size_t)Nn * 64 + 255)/256, 256, 0, stream>>>(m2f, m3_W, m3_b, out, Nn);
}

// Round 5
// 504.471 us; speedup vs baseline: 4.5406x; 1.0206x over previous
//
#include <hip/hip_runtime.h>
#include <math.h>

constexpr int HID = 1024;
constexpr float NEG_SLOPE = 0.2f;
constexpr float EPSV = 1e-16f;

typedef __bf16 bf16x8 __attribute__((ext_vector_type(8)));
typedef float f32x4 __attribute__((ext_vector_type(4)));
typedef unsigned short us4 __attribute__((ext_vector_type(4)));
typedef unsigned short ushort_t;

__device__ __forceinline__ float4 ld4(const float* p){ return *reinterpret_cast<const float4*>(p); }
__device__ __forceinline__ float b2f(ushort_t u){ return __uint_as_float(((unsigned)u) << 16); }
__device__ __forceinline__ ushort_t f2b(float f){
  unsigned u = __float_as_uint(f);
  return (ushort_t)((u + 0x7FFFu + ((u >> 16) & 1u)) >> 16);
}

// ---------------- weight transpose + f32->bf16: WT[n*K+k] = bf16(W[k*N+n]) ----------------
__global__ __launch_bounds__(256) void transpose_f2b(const float* __restrict__ W, ushort_t* __restrict__ WT,
                                                     int K, int N){
  __shared__ float tile[32][33];
  const int tx = threadIdx.x & 31, ty = threadIdx.x >> 5;  // 32 x 8
  const int n0 = blockIdx.x * 32, k0 = blockIdx.y * 32;
  #pragma unroll
  for (int r = 0; r < 32; r += 8)
    tile[ty + r][tx] = W[(size_t)(k0 + ty + r) * N + n0 + tx];
  __syncthreads();
  #pragma unroll
  for (int r = 0; r < 32; r += 8)
    WT[(size_t)(n0 + ty + r) * K + k0 + tx] = f2b(tile[tx][ty + r]);
}

// ---------------- f32 -> bf16 elementwise ----------------
__global__ void convert_f2b(const float* __restrict__ in, ushort_t* __restrict__ out, size_t n){
  size_t i = ((size_t)blockIdx.x * blockDim.x + threadIdx.x) * 4;
  const size_t stride = (size_t)gridDim.x * blockDim.x * 4;
  for (; i < n; i += stride){
    const float4 v = ld4(in + i);
    us4 o = {f2b(v.x), f2b(v.y), f2b(v.z), f2b(v.w)};
    *reinterpret_cast<us4*>(out + i) = o;
  }
}

// ---------------- bf16 MFMA GEMM: C = act(A[M,K] @ BT[N,K]^T + bias), 128x128 tile, BK=64 ----------------
template<int ACT, int OUTB>
__global__ __launch_bounds__(256, 2) void gemm_mfma(
    const ushort_t* __restrict__ A, const ushort_t* __restrict__ BT,
    const float* __restrict__ bias, float* __restrict__ Cf, ushort_t* __restrict__ Cb,
    int M, int K, int N)
{
  __shared__ __align__(16) ushort_t Asl[128 * 64];
  __shared__ __align__(16) ushort_t Bsl[128 * 64];
  const int tid = threadIdx.x;
  const int lane = tid & 63, wave = tid >> 6;
  const int wr = (wave >> 1) * 64, wc = (wave & 1) * 64;
  const int bm = blockIdx.y * 128, bn = blockIdx.x * 128;
  const int mrow = lane & 15;
  const int kof = (lane >> 4) * 8;

  f32x4 acc[4][4];
  #pragma unroll
  for (int i = 0; i < 4; ++i)
    #pragma unroll
    for (int j = 0; j < 4; ++j)
      acc[i][j] = (f32x4){0.f, 0.f, 0.f, 0.f};

  for (int k0 = 0; k0 < K; k0 += 64) {
    #pragma unroll
    for (int q = 0; q < 4; ++q) {
      const int c = q * 256 + tid;
      const int row = c >> 3, sl = (c & 7) * 8;
      int arow = bm + row; if (arow > M - 1) arow = M - 1;
      __builtin_amdgcn_global_load_lds(
        (const __attribute__((address_space(1))) unsigned int*)(A + (size_t)arow * K + k0 + sl),
        (__attribute__((address_space(3))) unsigned int*)(Asl + (size_t)(q * 256 + wave * 64) * 8),
        16, 0, 0);
      __builtin_amdgcn_global_load_lds(
        (const __attribute__((address_space(1))) unsigned int*)(BT + (size_t)(bn + row) * K + k0 + sl),
        (__attribute__((address_space(3))) unsigned int*)(Bsl + (size_t)(q * 256 + wave * 64) * 8),
        16, 0, 0);
    }
    __syncthreads();
    #pragma unroll
    for (int ks = 0; ks < 2; ++ks) {
      bf16x8 af[4], bfr[4];
      #pragma unroll
      for (int i = 0; i < 4; ++i)
        af[i] = *reinterpret_cast<const bf16x8*>(&Asl[(wr + i * 16 + mrow) * 64 + ks * 32 + kof]);
      #pragma unroll
      for (int j = 0; j < 4; ++j)
        bfr[j] = *reinterpret_cast<const bf16x8*>(&Bsl[(wc + j * 16 + mrow) * 64 + ks * 32 + kof]);
      #pragma unroll
      for (int i = 0; i < 4; ++i)
        #pragma unroll
        for (int j = 0; j < 4; ++j)
          acc[i][j] = __builtin_amdgcn_mfma_f32_16x16x32_bf16(af[i], bfr[j], acc[i][j], 0, 0, 0);
    }
    __syncthreads();
  }

  const int r0 = (lane >> 4) * 4;
  #pragma unroll
  for (int j = 0; j < 4; ++j) {
    const int col = bn + wc + j * 16 + mrow;
    const float bv = bias[col];
    #pragma unroll
    for (int i = 0; i < 4; ++i) {
      #pragma unroll
      for (int r = 0; r < 4; ++r) {
        const int row = bm + wr + i * 16 + r0 + r;
        if (row < M) {
          float t = acc[i][j][r] + bv;
          if (ACT == 1) t = fmaxf(t, 0.f);
          else if (ACT == 2) t = (t > 0.f) ? t : expm1f(t);
          if (OUTB) Cb[(size_t)row * N + col] = f2b(t);
          else      Cf[(size_t)row * N + col] = t;
        }
      }
    }
  }
}

// ---------------- CSR build ----------------
__global__ void count_deg(const int* __restrict__ dst, int* __restrict__ deg, int E){
  int e = blockIdx.x * blockDim.x + threadIdx.x;
  if (e < E) atomicAdd(&deg[dst[e]], 1);
}

__global__ __launch_bounds__(1024) void scan_offsets(const int* __restrict__ deg, int* __restrict__ offs, int n){
  __shared__ int sd[1024];
  const int tid = threadIdx.x;
  int running = 0;
  for (int base = 0; base < n; base += 1024){
    const int i = base + tid;
    const int v = (i < n) ? deg[i] : 0;
    sd[tid] = v;
    __syncthreads();
    for (int s = 1; s < 1024; s <<= 1){
      int t = (tid >= s) ? sd[tid - s] : 0;
      __syncthreads();
      sd[tid] += t;
      __syncthreads();
    }
    if (i < n) offs[i] = running + sd[tid] - v;
    running += sd[1023];
    __syncthreads();
  }
  if (tid == 0) offs[n] = running;
}

// fill CSR: store src and edge_attr (as float4) in dst-sorted position order
__global__ void fill_csr(const int* __restrict__ src, const int* __restrict__ dst,
                         const float* __restrict__ edge_attr,
                         const int* __restrict__ offs, int* __restrict__ cursor,
                         int* __restrict__ csr_src, float* __restrict__ csr_ea, int E){
  int e = blockIdx.x * blockDim.x + threadIdx.x;
  if (e < E){
    int d = dst[e];
    int pos = offs[d] + atomicAdd(&cursor[d], 1);
    csr_src[pos] = src[e];
    *reinterpret_cast<float4*>(csr_ea + (size_t)pos * 4) = ld4(edge_attr + (size_t)e * 4);
  }
}

// ---------------- fused GATv2: logits + online softmax + aggregate + bias + elu ----------------
// One block (256 thr) per dst node. Thread t owns dims [4t, 4t+4); head = t>>5.
// Processes 2 edges per iteration: one rescale per pair, native-exp softmax.
__global__ __launch_bounds__(256) void fused_gat(
    const int* __restrict__ offs, const int* __restrict__ csr_src, const float* __restrict__ csr_ea,
    const float* __restrict__ We, const float* __restrict__ att,
    const ushort_t* __restrict__ xlr, const float* __restrict__ bias,
    ushort_t* __restrict__ out, int N)
{
  const int n = blockIdx.x;
  const int t = threadIdx.x;
  const int d0 = t * 4;

  const float4 W0 = ld4(We + d0);
  const float4 W1 = ld4(We + 1024 + d0);
  const float4 W2 = ld4(We + 2048 + d0);
  const float4 W3 = ld4(We + 3072 + d0);
  const float4 AT = ld4(att + d0);
  const us4 xrv = *reinterpret_cast<const us4*>(xlr + (size_t)n * 2048 + 1024 + d0);
  const float xr0 = b2f(xrv[0]), xr1 = b2f(xrv[1]), xr2 = b2f(xrv[2]), xr3 = b2f(xrv[3]);

  const int o0 = offs[n], o1 = offs[n + 1];

  float acc0 = 0.f, acc1 = 0.f, acc2 = 0.f, acc3 = 0.f;
  float lsum = 0.f, mcur = -1e30f;

  us4 xv0 = {0,0,0,0}, xv1 = {0,0,0,0};
  float4 ea0 = make_float4(0.f,0.f,0.f,0.f), ea1 = ea0;
  if (o0 < o1){
    xv0 = *reinterpret_cast<const us4*>(xlr + (size_t)csr_src[o0] * 2048 + d0);
    ea0 = ld4(csr_ea + (size_t)o0 * 4);
  }
  if (o0 + 1 < o1){
    xv1 = *reinterpret_cast<const us4*>(xlr + (size_t)csr_src[o0 + 1] * 2048 + d0);
    ea1 = ld4(csr_ea + (size_t)(o0 + 1) * 4);
  }

  int i = o0;
  while (i < o1){
    const us4 xa = xv0; const float4 eA = ea0;
    const us4 xb = xv1; const float4 eB = ea1;
    const bool pair = (i + 1 < o1);
    const int ni = i + 2;
    if (ni < o1){
      xv0 = *reinterpret_cast<const us4*>(xlr + (size_t)csr_src[ni] * 2048 + d0);
      ea0 = ld4(csr_ea + (size_t)ni * 4);
    }
    if (ni + 1 < o1){
      xv1 = *reinterpret_cast<const us4*>(xlr + (size_t)csr_src[ni + 1] * 2048 + d0);
      ea1 = ld4(csr_ea + (size_t)(ni + 1) * 4);
    }

    const float xa0 = b2f(xa[0]), xa1 = b2f(xa[1]), xa2 = b2f(xa[2]), xa3 = b2f(xa[3]);
    const float xb0 = b2f(xb[0]), xb1 = b2f(xb[1]), xb2 = b2f(xb[2]), xb3 = b2f(xb[3]);

    float a0 = xa0 + xr0 + eA.x*W0.x + eA.y*W1.x + eA.z*W2.x + eA.w*W3.x;
    float a1 = xa1 + xr1 + eA.x*W0.y + eA.y*W1.y + eA.z*W2.y + eA.w*W3.y;
    float a2 = xa2 + xr2 + eA.x*W0.z + eA.y*W1.z + eA.z*W2.z + eA.w*W3.z;
    float a3 = xa3 + xr3 + eA.x*W0.w + eA.y*W1.w + eA.z*W2.w + eA.w*W3.w;
    float b0 = xb0 + xr0 + eB.x*W0.x + eB.y*W1.x + eB.z*W2.x + eB.w*W3.x;
    float b1 = xb1 + xr1 + eB.x*W0.y + eB.y*W1.y + eB.z*W2.y + eB.w*W3.y;
    float b2 = xb2 + xr2 + eB.x*W0.z + eB.y*W1.z + eB.z*W2.z + eB.w*W3.z;
    float b3 = xb3 + xr3 + eB.x*W0.w + eB.y*W1.w + eB.z*W2.w + eB.w*W3.w;
    a0 = (a0 > 0.f) ? a0 : NEG_SLOPE * a0;  a1 = (a1 > 0.f) ? a1 : NEG_SLOPE * a1;
    a2 = (a2 > 0.f) ? a2 : NEG_SLOPE * a2;  a3 = (a3 > 0.f) ? a3 : NEG_SLOPE * a3;
    b0 = (b0 > 0.f) ? b0 : NEG_SLOPE * b0;  b1 = (b1 > 0.f) ? b1 : NEG_SLOPE * b1;
    b2 = (b2 > 0.f) ? b2 : NEG_SLOPE * b2;  b3 = (b3 > 0.f) ? b3 : NEG_SLOPE * b3;
    float zA = a0*AT.x + a1*AT.y + a2*AT.z + a3*AT.w;
    float zB = b0*AT.x + b1*AT.y + b2*AT.z + b3*AT.w;
    #pragma unroll
    for (int sh = 1; sh <= 16; sh <<= 1){
      zA += __shfl_xor(zA, sh, 64);
      zB += __shfl_xor(zB, sh, 64);
    }

    if (pair){
      const float mn = fmaxf(fmaxf(mcur, zA), zB);
      const float sc = __expf(mcur - mn);
      const float pA = __expf(zA - mn);
      const float pB = __expf(zB - mn);
      lsum = lsum * sc + pA + pB;
      acc0 = acc0 * sc + pA * xa0 + pB * xb0;
      acc1 = acc1 * sc + pA * xa1 + pB * xb1;
      acc2 = acc2 * sc + pA * xa2 + pB * xb2;
      acc3 = acc3 * sc + pA * xa3 + pB * xb3;
      mcur = mn;
    } else {
      const float mn = fmaxf(mcur, zA);
      const float sc = __expf(mcur - mn);
      const float pA = __expf(zA - mn);
      lsum = lsum * sc + pA;
      acc0 = acc0 * sc + pA * xa0;
      acc1 = acc1 * sc + pA * xa1;
      acc2 = acc2 * sc + pA * xa2;
      acc3 = acc3 * sc + pA * xa3;
      mcur = mn;
    }
    i = ni;
  }

  const float r = 1.f / (lsum + EPSV);
  const float4 BV = ld4(bias + d0);
  float o0v = acc0 * r + BV.x;
  float o1v = acc1 * r + BV.y;
  float o2v = acc2 * r + BV.z;
  float o3v = acc3 * r + BV.w;
  o0v = (o0v > 0.f) ? o0v : expm1f(o0v);
  o1v = (o1v > 0.f) ? o1v : expm1f(o1v);
  o2v = (o2v > 0.f) ? o2v : expm1f(o2v);
  o3v = (o3v > 0.f) ? o3v : expm1f(o3v);
  us4 ov = {f2b(o0v), f2b(o1v), f2b(o2v), f2b(o3v)};
  *reinterpret_cast<us4*>(out + (size_t)n * HID + d0) = ov;
}

// ---------------- final matvec + sigmoid: one wave per row ----------------
__global__ __launch_bounds__(256) void mlp_final(const float* __restrict__ h, const float* __restrict__ w,
                                                 const float* __restrict__ b, float* __restrict__ out, int M)
{
  const int row = (int)((blockIdx.x * (size_t)blockDim.x + threadIdx.x) >> 6);
  const int lane = threadIdx.x & 63;
  if (row >= M) return;
  const float2 v  = *reinterpret_cast<const float2*>(&h[(size_t)row * 128 + lane * 2]);
  const float2 ww = *reinterpret_cast<const float2*>(&w[lane * 2]);
  float s = v.x * ww.x + v.y * ww.y;
  #pragma unroll
  for (int m = 1; m <= 32; m <<= 1) s += __shfl_xor(s, m, 64);
  if (lane == 0) out[row] = 1.f / (1.f + expf(-(s + b[0])));
}

extern "C" void kernel_launch(void* const* d_in, const int* in_sizes, int n_in,
                              void* d_out, int out_size, void* d_ws, size_t ws_size,
                              hipStream_t stream)
{
  const float* x        = (const float*)d_in[0];
  const int*   ei       = (const int*)d_in[1];
  const float* edge_attr= (const float*)d_in[2];
  const float* W_in     = (const float*)d_in[3];
  const float* b_in     = (const float*)d_in[4];
  const float* m1_W     = (const float*)d_in[5];
  const float* m1_b     = (const float*)d_in[6];
  const float* m2_W     = (const float*)d_in[7];
  const float* m2_b     = (const float*)d_in[8];
  const float* m3_W     = (const float*)d_in[9];
  const float* m3_b     = (const float*)d_in[10];
  const float* g_Wl[2]  = {(const float*)d_in[11], (const float*)d_in[18]};
  const float* g_bl[2]  = {(const float*)d_in[12], (const float*)d_in[19]};
  const float* g_Wr[2]  = {(const float*)d_in[13], (const float*)d_in[20]};
  const float* g_br[2]  = {(const float*)d_in[14], (const float*)d_in[21]};
  const float* g_We[2]  = {(const float*)d_in[15], (const float*)d_in[22]};
  const float* g_att[2] = {(const float*)d_in[16], (const float*)d_in[23]};
  const float* g_b[2]   = {(const float*)d_in[17], (const float*)d_in[24]};

  const int Nn = in_sizes[0] / 1024;
  const int E  = in_sizes[1] / 2;
  const int* srcv = ei;
  const int* dstv = ei + E;
  float* out = (float*)d_out;

  char* wsp = (char*)d_ws;
  size_t off = 0;
  auto alloc = [&](size_t bytes)->char* {
    char* p = wsp + off;
    off = (off + bytes + 255) & ~(size_t)255;
    return p;
  };
  ushort_t* hbf  = (ushort_t*)alloc((size_t)Nn * HID * 2);
  ushort_t* ubuf = (ushort_t*)alloc((size_t)Nn * HID * 2);       // x bf16, later m1 output
  ushort_t* xlr  = (ushort_t*)alloc((size_t)Nn * 2048 * 2);      // [xl | xr]
  float*    m2f  = (float*)   alloc((size_t)Nn * 128 * 4);
  ushort_t* WinT = (ushort_t*)alloc((size_t)1024 * 1024 * 2);
  ushort_t* Wlr0 = (ushort_t*)alloc((size_t)2048 * 1024 * 2);
  ushort_t* Wlr1 = (ushort_t*)alloc((size_t)2048 * 1024 * 2);
  ushort_t* m1T  = (ushort_t*)alloc((size_t)512 * 1024 * 2);
  ushort_t* m2T  = (ushort_t*)alloc((size_t)128 * 512 * 2);
  float*  biasc  = (float*)   alloc((size_t)2048 * 2 * 4);       // concat biases, both layers
  int* deg    = (int*)alloc((size_t)Nn * 2 * 4);
  int* cursor = deg + Nn;
  int* offs   = (int*)alloc((size_t)(Nn + 1) * 4);
  int* csr_src= (int*)alloc((size_t)E * 4);
  float* csr_ea = (float*)alloc((size_t)E * 4 * 4);
  ushort_t* Wlr[2]  = {Wlr0, Wlr1};
  float*    blr[2]  = {biasc, biasc + 2048};

  // --- weight prep: transposed bf16, Wl/Wr merged; concat biases (d2d copies) ---
  transpose_f2b<<<dim3(32, 32), 256, 0, stream>>>(W_in, WinT, 1024, 1024);
  transpose_f2b<<<dim3(32, 32), 256, 0, stream>>>(g_Wl[0], Wlr0,              1024, 1024);
  transpose_f2b<<<dim3(32, 32), 256, 0, stream>>>(g_Wr[0], Wlr0 + 1024*1024,  1024, 1024);
  transpose_f2b<<<dim3(32, 32), 256, 0, stream>>>(g_Wl[1], Wlr1,              1024, 1024);
  transpose_f2b<<<dim3(32, 32), 256, 0, stream>>>(g_Wr[1], Wlr1 + 1024*1024,  1024, 1024);
  transpose_f2b<<<dim3(16, 32), 256, 0, stream>>>(m1_W, m1T, 1024, 512);
  transpose_f2b<<<dim3(4, 16), 256, 0, stream>>>(m2_W, m2T, 512, 128);
  convert_f2b<<<2048, 256, 0, stream>>>(x, ubuf, (size_t)Nn * HID);
  hipMemcpyAsync(biasc,        g_bl[0], 1024*4, hipMemcpyDeviceToDevice, stream);
  hipMemcpyAsync(biasc + 1024, g_br[0], 1024*4, hipMemcpyDeviceToDevice, stream);
  hipMemcpyAsync(biasc + 2048, g_bl[1], 1024*4, hipMemcpyDeviceToDevice, stream);
  hipMemcpyAsync(biasc + 3072, g_br[1], 1024*4, hipMemcpyDeviceToDevice, stream);

  // --- CSR by dst ---
  hipMemsetAsync(deg, 0, (size_t)Nn * 2 * 4, stream);
  count_deg<<<(E + 255)/256, 256, 0, stream>>>(dstv, deg, E);
  scan_offsets<<<1, 1024, 0, stream>>>(deg, offs, Nn);
  fill_csr<<<(E + 255)/256, 256, 0, stream>>>(srcv, dstv, edge_attr, offs, cursor, csr_src, csr_ea, E);

  const int MB = (Nn + 127) / 128;
  // h0 = elu(x @ W_in + b_in) -> hbf (bf16)
  gemm_mfma<2, 1><<<dim3(8, MB), 256, 0, stream>>>(ubuf, WinT, b_in, nullptr, hbf, Nn, 1024, 1024);

  for (int L = 0; L < 2; ++L){
    gemm_mfma<0, 1><<<dim3(16, MB), 256, 0, stream>>>(hbf, Wlr[L], blr[L], nullptr, xlr, Nn, 1024, 2048);
    fused_gat<<<Nn, 256, 0, stream>>>(offs, csr_src, csr_ea, g_We[L], g_att[L], xlr, g_b[L], hbf, Nn);
  }

  // MLP
  gemm_mfma<1, 1><<<dim3(4, MB), 256, 0, stream>>>(hbf, m1T, m1_b, nullptr, ubuf, Nn, 1024, 512);
  gemm_mfma<1, 0><<<dim3(1, MB), 256, 0, stream>>>(ubuf, m2T, m2_b, m2f, nullptr, Nn, 512, 128);
  mlp_final<<<((size_t)Nn * 64 + 255)/256, 256, 0, stream>>>(m2f, m3_W, m3_b, out, Nn);
}

// Round 6
// 456.793 us; speedup vs baseline: 5.0146x; 1.1044x over previous
//
#include <hip/hip_runtime.h>
#include <math.h>

constexpr int HID = 1024;
constexpr float NEG_SLOPE = 0.2f;
constexpr float EPSV = 1e-16f;

typedef __bf16 bf16x8 __attribute__((ext_vector_type(8)));
typedef float f32x4 __attribute__((ext_vector_type(4)));
typedef float f32x2 __attribute__((ext_vector_type(2)));
typedef unsigned short us4 __attribute__((ext_vector_type(4)));
typedef unsigned short ushort_t;

__device__ __forceinline__ float4 ld4(const float* p){ return *reinterpret_cast<const float4*>(p); }
__device__ __forceinline__ float b2f(ushort_t u){ return __uint_as_float(((unsigned)u) << 16); }
__device__ __forceinline__ ushort_t f2b(float f){
  unsigned u = __float_as_uint(f);
  return (ushort_t)((u + 0x7FFFu + ((u >> 16) & 1u)) >> 16);
}
__device__ __forceinline__ float rfl(float x){
  return __uint_as_float(__builtin_amdgcn_readfirstlane(__float_as_uint(x)));
}
// unpack 2 packed bf16 (one u32) -> f32x2
__device__ __forceinline__ f32x2 up2(unsigned u){
  f32x2 r;
  r[0] = __uint_as_float(u << 16);
  r[1] = __uint_as_float(u & 0xffff0000u);
  return r;
}
__device__ __forceinline__ f32x2 lrelu2(f32x2 v){
  return __builtin_elementwise_max(v, v * NEG_SLOPE);
}

// ---------------- weight transpose + f32->bf16: WT[n*K+k] = bf16(W[k*N+n]) ----------------
__global__ __launch_bounds__(256) void transpose_f2b(const float* __restrict__ W, ushort_t* __restrict__ WT,
                                                     int K, int N){
  __shared__ float tile[32][33];
  const int tx = threadIdx.x & 31, ty = threadIdx.x >> 5;  // 32 x 8
  const int n0 = blockIdx.x * 32, k0 = blockIdx.y * 32;
  #pragma unroll
  for (int r = 0; r < 32; r += 8)
    tile[ty + r][tx] = W[(size_t)(k0 + ty + r) * N + n0 + tx];
  __syncthreads();
  #pragma unroll
  for (int r = 0; r < 32; r += 8)
    WT[(size_t)(n0 + ty + r) * K + k0 + tx] = f2b(tile[tx][ty + r]);
}

// ---------------- f32 -> bf16 elementwise ----------------
__global__ void convert_f2b(const float* __restrict__ in, ushort_t* __restrict__ out, size_t n){
  size_t i = ((size_t)blockIdx.x * blockDim.x + threadIdx.x) * 4;
  const size_t stride = (size_t)gridDim.x * blockDim.x * 4;
  for (; i < n; i += stride){
    const float4 v = ld4(in + i);
    us4 o = {f2b(v.x), f2b(v.y), f2b(v.z), f2b(v.w)};
    *reinterpret_cast<us4*>(out + i) = o;
  }
}

// ---------------- bf16 MFMA GEMM: C = act(A[M,K] @ BT[N,K]^T + bias), 128x128 tile, BK=64 ----------------
// XCD-aware bijective block swizzle (m204) for L2 locality.
template<int ACT, int OUTB>
__global__ __launch_bounds__(256, 2) void gemm_mfma(
    const ushort_t* __restrict__ A, const ushort_t* __restrict__ BT,
    const float* __restrict__ bias, float* __restrict__ Cf, ushort_t* __restrict__ Cb,
    int M, int K, int N)
{
  __shared__ __align__(16) ushort_t Asl[128 * 64];
  __shared__ __align__(16) ushort_t Bsl[128 * 64];
  const int tid = threadIdx.x;
  const int lane = tid & 63, wave = tid >> 6;
  const int wr = (wave >> 1) * 64, wc = (wave & 1) * 64;

  // bijective XCD swizzle
  const int nwg = gridDim.x * gridDim.y;
  int wg = blockIdx.y * gridDim.x + blockIdx.x;
  {
    const int q = nwg >> 3, r = nwg & 7;
    const int xcd = wg & 7, lo = wg >> 3;
    wg = (xcd < r ? xcd * (q + 1) : r * (q + 1) + (xcd - r) * q) + lo;
  }
  const int bm = (wg / gridDim.x) * 128, bn = (wg % gridDim.x) * 128;

  const int mrow = lane & 15;
  const int kof = (lane >> 4) * 8;

  f32x4 acc[4][4];
  #pragma unroll
  for (int i = 0; i < 4; ++i)
    #pragma unroll
    for (int j = 0; j < 4; ++j)
      acc[i][j] = (f32x4){0.f, 0.f, 0.f, 0.f};

  for (int k0 = 0; k0 < K; k0 += 64) {
    #pragma unroll
    for (int q = 0; q < 4; ++q) {
      const int c = q * 256 + tid;
      const int row = c >> 3, sl = (c & 7) * 8;
      int arow = bm + row; if (arow > M - 1) arow = M - 1;
      __builtin_amdgcn_global_load_lds(
        (const __attribute__((address_space(1))) unsigned int*)(A + (size_t)arow * K + k0 + sl),
        (__attribute__((address_space(3))) unsigned int*)(Asl + (size_t)(q * 256 + wave * 64) * 8),
        16, 0, 0);
      __builtin_amdgcn_global_load_lds(
        (const __attribute__((address_space(1))) unsigned int*)(BT + (size_t)(bn + row) * K + k0 + sl),
        (__attribute__((address_space(3))) unsigned int*)(Bsl + (size_t)(q * 256 + wave * 64) * 8),
        16, 0, 0);
    }
    __syncthreads();
    #pragma unroll
    for (int ks = 0; ks < 2; ++ks) {
      bf16x8 af[4], bfr[4];
      #pragma unroll
      for (int i = 0; i < 4; ++i)
        af[i] = *reinterpret_cast<const bf16x8*>(&Asl[(wr + i * 16 + mrow) * 64 + ks * 32 + kof]);
      #pragma unroll
      for (int j = 0; j < 4; ++j)
        bfr[j] = *reinterpret_cast<const bf16x8*>(&Bsl[(wc + j * 16 + mrow) * 64 + ks * 32 + kof]);
      #pragma unroll
      for (int i = 0; i < 4; ++i)
        #pragma unroll
        for (int j = 0; j < 4; ++j)
          acc[i][j] = __builtin_amdgcn_mfma_f32_16x16x32_bf16(af[i], bfr[j], acc[i][j], 0, 0, 0);
    }
    __syncthreads();
  }

  const int r0 = (lane >> 4) * 4;
  #pragma unroll
  for (int j = 0; j < 4; ++j) {
    const int col = bn + wc + j * 16 + mrow;
    const float bv = bias[col];
    #pragma unroll
    for (int i = 0; i < 4; ++i) {
      #pragma unroll
      for (int r = 0; r < 4; ++r) {
        const int row = bm + wr + i * 16 + r0 + r;
        if (row < M) {
          float t = acc[i][j][r] + bv;
          if (ACT == 1) t = fmaxf(t, 0.f);
          else if (ACT == 2) t = (t > 0.f) ? t : expm1f(t);
          if (OUTB) Cb[(size_t)row * N + col] = f2b(t);
          else      Cf[(size_t)row * N + col] = t;
        }
      }
    }
  }
}

// ---------------- CSR build ----------------
__global__ void count_deg(const int* __restrict__ dst, int* __restrict__ deg, int E){
  int e = blockIdx.x * blockDim.x + threadIdx.x;
  if (e < E) atomicAdd(&deg[dst[e]], 1);
}

__global__ __launch_bounds__(1024) void scan_offsets(const int* __restrict__ deg, int* __restrict__ offs, int n){
  __shared__ int sd[1024];
  const int tid = threadIdx.x;
  int running = 0;
  for (int base = 0; base < n; base += 1024){
    const int i = base + tid;
    const int v = (i < n) ? deg[i] : 0;
    sd[tid] = v;
    __syncthreads();
    for (int s = 1; s < 1024; s <<= 1){
      int t = (tid >= s) ? sd[tid - s] : 0;
      __syncthreads();
      sd[tid] += t;
      __syncthreads();
    }
    if (i < n) offs[i] = running + sd[tid] - v;
    running += sd[1023];
    __syncthreads();
  }
  if (tid == 0) offs[n] = running;
}

// fill CSR: store src and edge_attr (as float4) in dst-sorted position order
__global__ void fill_csr(const int* __restrict__ src, const int* __restrict__ dst,
                         const float* __restrict__ edge_attr,
                         const int* __restrict__ offs, int* __restrict__ cursor,
                         int* __restrict__ csr_src, float* __restrict__ csr_ea, int E){
  int e = blockIdx.x * blockDim.x + threadIdx.x;
  if (e < E){
    int d = dst[e];
    int pos = offs[d] + atomicAdd(&cursor[d], 1);
    csr_src[pos] = src[e];
    *reinterpret_cast<float4*>(csr_ea + (size_t)pos * 4) = ld4(edge_attr + (size_t)e * 4);
  }
}

// ---------------- fused GATv2: logits + online softmax + aggregate + bias + elu ----------------
// One block (256 thr) per dst node. Thread t owns dims [4t, 4t+4); head = t>>5.
// Uniform values scalarized to SGPRs; math in packed f32x2 (v_pk_*); 2 edges/iter.
__global__ __launch_bounds__(256) void fused_gat(
    const int* __restrict__ offs, const int* __restrict__ csr_src, const float* __restrict__ csr_ea,
    const float* __restrict__ We, const float* __restrict__ att,
    const ushort_t* __restrict__ xlr, const float* __restrict__ bias,
    ushort_t* __restrict__ out, int N)
{
  const int n = blockIdx.x;
  const int t = threadIdx.x;
  const int d0 = t * 4;

  const float4 W0 = ld4(We + d0);
  const float4 W1 = ld4(We + 1024 + d0);
  const float4 W2 = ld4(We + 2048 + d0);
  const float4 W3 = ld4(We + 3072 + d0);
  const float4 AT = ld4(att + d0);
  const f32x2 W0l = {W0.x, W0.y}, W0h = {W0.z, W0.w};
  const f32x2 W1l = {W1.x, W1.y}, W1h = {W1.z, W1.w};
  const f32x2 W2l = {W2.x, W2.y}, W2h = {W2.z, W2.w};
  const f32x2 W3l = {W3.x, W3.y}, W3h = {W3.z, W3.w};
  const f32x2 ATl = {AT.x, AT.y}, ATh = {AT.z, AT.w};

  const uint2 xru = *reinterpret_cast<const uint2*>(xlr + (size_t)n * 2048 + 1024 + d0);
  const f32x2 xrl = up2(xru.x), xrh = up2(xru.y);

  const int o0 = __builtin_amdgcn_readfirstlane(offs[n]);
  const int o1 = __builtin_amdgcn_readfirstlane(offs[n + 1]);

  f32x2 accl = {0.f, 0.f}, acch = {0.f, 0.f};
  float lsum = 0.f, mcur = -1e30f;

  uint2 xa = {0u, 0u}, xb = {0u, 0u};
  float eA0=0.f,eA1=0.f,eA2=0.f,eA3=0.f, eB0=0.f,eB1=0.f,eB2=0.f,eB3=0.f;

  auto ldedge = [&](int idx, uint2& xv, float& e0, float& e1, float& e2, float& e3){
    const int s = __builtin_amdgcn_readfirstlane(csr_src[idx]);   // SGPR
    xv = *reinterpret_cast<const uint2*>(xlr + (size_t)s * 2048 + d0);  // SGPR base + const voffset
    const float4 e = ld4(csr_ea + (size_t)idx * 4);
    e0 = rfl(e.x); e1 = rfl(e.y); e2 = rfl(e.z); e3 = rfl(e.w);   // SGPRs
  };

  if (o0 < o1)     ldedge(o0,     xa, eA0,eA1,eA2,eA3);
  if (o0 + 1 < o1) ldedge(o0 + 1, xb, eB0,eB1,eB2,eB3);

  int i = o0;
  while (i < o1){
    const uint2 ca = xa; const float a0=eA0,a1=eA1,a2=eA2,a3=eA3;
    const uint2 cb = xb; const float b0=eB0,b1=eB1,b2=eB2,b3=eB3;
    const bool pair = (i + 1 < o1);
    const int ni = i + 2;
    if (ni < o1)     ldedge(ni,     xa, eA0,eA1,eA2,eA3);
    if (ni + 1 < o1) ldedge(ni + 1, xb, eB0,eB1,eB2,eB3);

    const f32x2 xal = up2(ca.x), xah = up2(ca.y);
    const f32x2 xbl = up2(cb.x), xbh = up2(cb.y);

    f32x2 mal = xal + xrl;  mal += a0*W0l; mal += a1*W1l; mal += a2*W2l; mal += a3*W3l;
    f32x2 mah = xah + xrh;  mah += a0*W0h; mah += a1*W1h; mah += a2*W2h; mah += a3*W3h;
    f32x2 mbl = xbl + xrl;  mbl += b0*W0l; mbl += b1*W1l; mbl += b2*W2l; mbl += b3*W3l;
    f32x2 mbh = xbh + xrh;  mbh += b0*W0h; mbh += b1*W1h; mbh += b2*W2h; mbh += b3*W3h;
    mal = lrelu2(mal); mah = lrelu2(mah); mbl = lrelu2(mbl); mbh = lrelu2(mbh);
    f32x2 za2 = mal * ATl;  za2 += mah * ATh;
    f32x2 zb2 = mbl * ATl;  zb2 += mbh * ATh;
    float zA = za2[0] + za2[1];
    float zB = zb2[0] + zb2[1];
    #pragma unroll
    for (int sh = 1; sh <= 16; sh <<= 1){
      zA += __shfl_xor(zA, sh, 64);
      zB += __shfl_xor(zB, sh, 64);
    }

    if (pair){
      const float mn = fmaxf(fmaxf(mcur, zA), zB);
      const float sc = __expf(mcur - mn);
      const float pA = __expf(zA - mn);
      const float pB = __expf(zB - mn);
      lsum = lsum * sc + pA + pB;
      const f32x2 scv = {sc, sc}, pAv = {pA, pA}, pBv = {pB, pB};
      accl = accl * scv + pAv * xal + pBv * xbl;
      acch = acch * scv + pAv * xah + pBv * xbh;
      mcur = mn;
    } else {
      const float mn = fmaxf(mcur, zA);
      const float sc = __expf(mcur - mn);
      const float pA = __expf(zA - mn);
      lsum = lsum * sc + pA;
      const f32x2 scv = {sc, sc}, pAv = {pA, pA};
      accl = accl * scv + pAv * xal;
      acch = acch * scv + pAv * xah;
      mcur = mn;
    }
    i = ni;
  }

  const float r = 1.f / (lsum + EPSV);
  const float4 BV = ld4(bias + d0);
  float o0v = accl[0] * r + BV.x;
  float o1v = accl[1] * r + BV.y;
  float o2v = acch[0] * r + BV.z;
  float o3v = acch[1] * r + BV.w;
  o0v = (o0v > 0.f) ? o0v : expm1f(o0v);
  o1v = (o1v > 0.f) ? o1v : expm1f(o1v);
  o2v = (o2v > 0.f) ? o2v : expm1f(o2v);
  o3v = (o3v > 0.f) ? o3v : expm1f(o3v);
  us4 ov = {f2b(o0v), f2b(o1v), f2b(o2v), f2b(o3v)};
  *reinterpret_cast<us4*>(out + (size_t)n * HID + d0) = ov;
}

// ---------------- final matvec + sigmoid: one wave per row ----------------
__global__ __launch_bounds__(256) void mlp_final(const float* __restrict__ h, const float* __restrict__ w,
                                                 const float* __restrict__ b, float* __restrict__ out, int M)
{
  const int row = (int)((blockIdx.x * (size_t)blockDim.x + threadIdx.x) >> 6);
  const int lane = threadIdx.x & 63;
  if (row >= M) return;
  const float2 v  = *reinterpret_cast<const float2*>(&h[(size_t)row * 128 + lane * 2]);
  const float2 ww = *reinterpret_cast<const float2*>(&w[lane * 2]);
  float s = v.x * ww.x + v.y * ww.y;
  #pragma unroll
  for (int m = 1; m <= 32; m <<= 1) s += __shfl_xor(s, m, 64);
  if (lane == 0) out[row] = 1.f / (1.f + expf(-(s + b[0])));
}

extern "C" void kernel_launch(void* const* d_in, const int* in_sizes, int n_in,
                              void* d_out, int out_size, void* d_ws, size_t ws_size,
                              hipStream_t stream)
{
  const float* x        = (const float*)d_in[0];
  const int*   ei       = (const int*)d_in[1];
  const float* edge_attr= (const float*)d_in[2];
  const float* W_in     = (const float*)d_in[3];
  const float* b_in     = (const float*)d_in[4];
  const float* m1_W     = (const float*)d_in[5];
  const float* m1_b     = (const float*)d_in[6];
  const float* m2_W     = (const float*)d_in[7];
  const float* m2_b     = (const float*)d_in[8];
  const float* m3_W     = (const float*)d_in[9];
  const float* m3_b     = (const float*)d_in[10];
  const float* g_Wl[2]  = {(const float*)d_in[11], (const float*)d_in[18]};
  const float* g_bl[2]  = {(const float*)d_in[12], (const float*)d_in[19]};
  const float* g_Wr[2]  = {(const float*)d_in[13], (const float*)d_in[20]};
  const float* g_br[2]  = {(const float*)d_in[14], (const float*)d_in[21]};
  const float* g_We[2]  = {(const float*)d_in[15], (const float*)d_in[22]};
  const float* g_att[2] = {(const float*)d_in[16], (const float*)d_in[23]};
  const float* g_b[2]   = {(const float*)d_in[17], (const float*)d_in[24]};

  const int Nn = in_sizes[0] / 1024;
  const int E  = in_sizes[1] / 2;
  const int* srcv = ei;
  const int* dstv = ei + E;
  float* out = (float*)d_out;

  char* wsp = (char*)d_ws;
  size_t off = 0;
  auto alloc = [&](size_t bytes)->char* {
    char* p = wsp + off;
    off = (off + bytes + 255) & ~(size_t)255;
    return p;
  };
  ushort_t* hbf  = (ushort_t*)alloc((size_t)Nn * HID * 2);
  ushort_t* ubuf = (ushort_t*)alloc((size_t)Nn * HID * 2);       // x bf16, later m1 output
  ushort_t* xlr  = (ushort_t*)alloc((size_t)Nn * 2048 * 2);      // [xl | xr]
  float*    m2f  = (float*)   alloc((size_t)Nn * 128 * 4);
  ushort_t* WinT = (ushort_t*)alloc((size_t)1024 * 1024 * 2);
  ushort_t* Wlr0 = (ushort_t*)alloc((size_t)2048 * 1024 * 2);
  ushort_t* Wlr1 = (ushort_t*)alloc((size_t)2048 * 1024 * 2);
  ushort_t* m1T  = (ushort_t*)alloc((size_t)512 * 1024 * 2);
  ushort_t* m2T  = (ushort_t*)alloc((size_t)128 * 512 * 2);
  float*  biasc  = (float*)   alloc((size_t)2048 * 2 * 4);       // concat biases, both layers
  int* deg    = (int*)alloc((size_t)Nn * 2 * 4);
  int* cursor = deg + Nn;
  int* offs   = (int*)alloc((size_t)(Nn + 1) * 4);
  int* csr_src= (int*)alloc((size_t)E * 4);
  float* csr_ea = (float*)alloc((size_t)E * 4 * 4);
  ushort_t* Wlr[2]  = {Wlr0, Wlr1};
  float*    blr[2]  = {biasc, biasc + 2048};

  // --- weight prep: transposed bf16, Wl/Wr merged; concat biases (d2d copies) ---
  transpose_f2b<<<dim3(32, 32), 256, 0, stream>>>(W_in, WinT, 1024, 1024);
  transpose_f2b<<<dim3(32, 32), 256, 0, stream>>>(g_Wl[0], Wlr0,              1024, 1024);
  transpose_f2b<<<dim3(32, 32), 256, 0, stream>>>(g_Wr[0], Wlr0 + 1024*1024,  1024, 1024);
  transpose_f2b<<<dim3(32, 32), 256, 0, stream>>>(g_Wl[1], Wlr1,              1024, 1024);
  transpose_f2b<<<dim3(32, 32), 256, 0, stream>>>(g_Wr[1], Wlr1 + 1024*1024,  1024, 1024);
  transpose_f2b<<<dim3(16, 32), 256, 0, stream>>>(m1_W, m1T, 1024, 512);
  transpose_f2b<<<dim3(4, 16), 256, 0, stream>>>(m2_W, m2T, 512, 128);
  convert_f2b<<<2048, 256, 0, stream>>>(x, ubuf, (size_t)Nn * HID);
  hipMemcpyAsync(biasc,        g_bl[0], 1024*4, hipMemcpyDeviceToDevice, stream);
  hipMemcpyAsync(biasc + 1024, g_br[0], 1024*4, hipMemcpyDeviceToDevice, stream);
  hipMemcpyAsync(biasc + 2048, g_bl[1], 1024*4, hipMemcpyDeviceToDevice, stream);
  hipMemcpyAsync(biasc + 3072, g_br[1], 1024*4, hipMemcpyDeviceToDevice, stream);

  // --- CSR by dst ---
  hipMemsetAsync(deg, 0, (size_t)Nn * 2 * 4, stream);
  count_deg<<<(E + 255)/256, 256, 0, stream>>>(dstv, deg, E);
  scan_offsets<<<1, 1024, 0, stream>>>(deg, offs, Nn);
  fill_csr<<<(E + 255)/256, 256, 0, stream>>>(srcv, dstv, edge_attr, offs, cursor, csr_src, csr_ea, E);

  const int MB = (Nn + 127) / 128;
  // h0 = elu(x @ W_in + b_in) -> hbf (bf16)
  gemm_mfma<2, 1><<<dim3(8, MB), 256, 0, stream>>>(ubuf, WinT, b_in, nullptr, hbf, Nn, 1024, 1024);

  for (int L = 0; L < 2; ++L){
    gemm_mfma<0, 1><<<dim3(16, MB), 256, 0, stream>>>(hbf, Wlr[L], blr[L], nullptr, xlr, Nn, 1024, 2048);
    fused_gat<<<Nn, 256, 0, stream>>>(offs, csr_src, csr_ea, g_We[L], g_att[L], xlr, g_b[L], hbf, Nn);
  }

  // MLP
  gemm_mfma<1, 1><<<dim3(4, MB), 256, 0, stream>>>(hbf, m1T, m1_b, nullptr, ubuf, Nn, 1024, 512);
  gemm_mfma<1, 0><<<dim3(1, MB), 256, 0, stream>>>(ubuf, m2T, m2_b, m2f, nullptr, Nn, 512, 128);
  mlp_final<<<((size_t)Nn * 64 + 255)/256, 256, 0, stream>>>(m2f, m3_W, m3_b, out, Nn);
}

// Round 7
// 423.435 us; speedup vs baseline: 5.4096x; 1.0788x over previous
//
#include <hip/hip_runtime.h>
#include <math.h>

constexpr int HID = 1024;
constexpr float NEG_SLOPE = 0.2f;
constexpr float EPSV = 1e-16f;

typedef __bf16 bf16x8 __attribute__((ext_vector_type(8)));
typedef float f32x4 __attribute__((ext_vector_type(4)));
typedef float f32x2 __attribute__((ext_vector_type(2)));
typedef unsigned short us8 __attribute__((ext_vector_type(8)));
typedef unsigned short us4 __attribute__((ext_vector_type(4)));
typedef unsigned short ushort_t;

__device__ __forceinline__ float4 ld4(const float* p){ return *reinterpret_cast<const float4*>(p); }
__device__ __forceinline__ float b2f(ushort_t u){ return __uint_as_float(((unsigned)u) << 16); }
__device__ __forceinline__ ushort_t f2b(float f){
  unsigned u = __float_as_uint(f);
  return (ushort_t)((u + 0x7FFFu + ((u >> 16) & 1u)) >> 16);
}
__device__ __forceinline__ float rfl(float x){
  return __uint_as_float(__builtin_amdgcn_readfirstlane(__float_as_uint(x)));
}
__device__ __forceinline__ f32x2 up2(unsigned u){
  f32x2 r;
  r[0] = __uint_as_float(u << 16);
  r[1] = __uint_as_float(u & 0xffff0000u);
  return r;
}
__device__ __forceinline__ f32x2 lrelu2(f32x2 v){
  return __builtin_elementwise_max(v, v * NEG_SLOPE);
}

// ---------------- batched weight transpose + f32->bf16 (five 1024x1024 mats) ----------------
struct TP5 { const float* src[5]; ushort_t* dst[5]; };
__global__ __launch_bounds__(256) void transpose_f2b_5(TP5 p){
  const int z = blockIdx.z;
  const float* W = p.src[z];
  ushort_t* WT = p.dst[z];
  __shared__ float tile[32][33];
  const int tx = threadIdx.x & 31, ty = threadIdx.x >> 5;
  const int n0 = blockIdx.x * 32, k0 = blockIdx.y * 32;
  #pragma unroll
  for (int r = 0; r < 32; r += 8)
    tile[ty + r][tx] = W[(size_t)(k0 + ty + r) * 1024 + n0 + tx];
  __syncthreads();
  #pragma unroll
  for (int r = 0; r < 32; r += 8)
    WT[(size_t)(n0 + ty + r) * 1024 + k0 + tx] = f2b(tile[tx][ty + r]);
}

// ---------------- single transpose (for m1/m2) ----------------
__global__ __launch_bounds__(256) void transpose_f2b(const float* __restrict__ W, ushort_t* __restrict__ WT,
                                                     int K, int N){
  __shared__ float tile[32][33];
  const int tx = threadIdx.x & 31, ty = threadIdx.x >> 5;
  const int n0 = blockIdx.x * 32, k0 = blockIdx.y * 32;
  #pragma unroll
  for (int r = 0; r < 32; r += 8)
    tile[ty + r][tx] = W[(size_t)(k0 + ty + r) * N + n0 + tx];
  __syncthreads();
  #pragma unroll
  for (int r = 0; r < 32; r += 8)
    WT[(size_t)(n0 + ty + r) * K + k0 + tx] = f2b(tile[tx][ty + r]);
}

// ---------------- bias concat (4 x 1024 f32) ----------------
struct BC4 { const float* s[4]; };
__global__ void concat_bias(BC4 p, float* __restrict__ dst){
  const int i = blockIdx.x * blockDim.x + threadIdx.x;   // 4096 total
  dst[i] = p.s[i >> 10][i & 1023];
}

// ---------------- f32 -> bf16 elementwise ----------------
__global__ void convert_f2b(const float* __restrict__ in, ushort_t* __restrict__ out, size_t n){
  size_t i = ((size_t)blockIdx.x * blockDim.x + threadIdx.x) * 4;
  const size_t stride = (size_t)gridDim.x * blockDim.x * 4;
  for (; i < n; i += stride){
    const float4 v = ld4(in + i);
    us4 o = {f2b(v.x), f2b(v.y), f2b(v.z), f2b(v.w)};
    *reinterpret_cast<us4*>(out + i) = o;
  }
}

// ---------------- bf16 MFMA GEMM: C = act(A[M,K] @ BT[N,K]^T + bias), 128x128 tile, BK=64 ----------------
template<int ACT, int OUTB>
__global__ __launch_bounds__(256, 3) void gemm_mfma(
    const ushort_t* __restrict__ A, const ushort_t* __restrict__ BT,
    const float* __restrict__ bias, float* __restrict__ Cf, ushort_t* __restrict__ Cb,
    int M, int K, int N)
{
  __shared__ __align__(16) ushort_t Asl[128 * 64];
  __shared__ __align__(16) ushort_t Bsl[128 * 64];
  const int tid = threadIdx.x;
  const int lane = tid & 63, wave = tid >> 6;
  const int wr = (wave >> 1) * 64, wc = (wave & 1) * 64;

  // bijective XCD swizzle
  const int nwg = gridDim.x * gridDim.y;
  int wg = blockIdx.y * gridDim.x + blockIdx.x;
  {
    const int q = nwg >> 3, r = nwg & 7;
    const int xcd = wg & 7, lo = wg >> 3;
    wg = (xcd < r ? xcd * (q + 1) : r * (q + 1) + (xcd - r) * q) + lo;
  }
  const int bm = (wg / gridDim.x) * 128, bn = (wg % gridDim.x) * 128;

  const int mrow = lane & 15;
  const int kof = (lane >> 4) * 8;

  f32x4 acc[4][4];
  #pragma unroll
  for (int i = 0; i < 4; ++i)
    #pragma unroll
    for (int j = 0; j < 4; ++j)
      acc[i][j] = (f32x4){0.f, 0.f, 0.f, 0.f};

  for (int k0 = 0; k0 < K; k0 += 64) {
    #pragma unroll
    for (int q = 0; q < 4; ++q) {
      const int c = q * 256 + tid;
      const int row = c >> 3, sl = (c & 7) * 8;
      int arow = bm + row; if (arow > M - 1) arow = M - 1;
      __builtin_amdgcn_global_load_lds(
        (const __attribute__((address_space(1))) unsigned int*)(A + (size_t)arow * K + k0 + sl),
        (__attribute__((address_space(3))) unsigned int*)(Asl + (size_t)(q * 256 + wave * 64) * 8),
        16, 0, 0);
      __builtin_amdgcn_global_load_lds(
        (const __attribute__((address_space(1))) unsigned int*)(BT + (size_t)(bn + row) * K + k0 + sl),
        (__attribute__((address_space(3))) unsigned int*)(Bsl + (size_t)(q * 256 + wave * 64) * 8),
        16, 0, 0);
    }
    __syncthreads();
    #pragma unroll
    for (int ks = 0; ks < 2; ++ks) {
      bf16x8 af[4], bfr[4];
      #pragma unroll
      for (int i = 0; i < 4; ++i)
        af[i] = *reinterpret_cast<const bf16x8*>(&Asl[(wr + i * 16 + mrow) * 64 + ks * 32 + kof]);
      #pragma unroll
      for (int j = 0; j < 4; ++j)
        bfr[j] = *reinterpret_cast<const bf16x8*>(&Bsl[(wc + j * 16 + mrow) * 64 + ks * 32 + kof]);
      #pragma unroll
      for (int i = 0; i < 4; ++i)
        #pragma unroll
        for (int j = 0; j < 4; ++j)
          acc[i][j] = __builtin_amdgcn_mfma_f32_16x16x32_bf16(af[i], bfr[j], acc[i][j], 0, 0, 0);
    }
    __syncthreads();
  }

  const int r0 = (lane >> 4) * 4;
  #pragma unroll
  for (int j = 0; j < 4; ++j) {
    const int col = bn + wc + j * 16 + mrow;
    const float bv = bias[col];
    #pragma unroll
    for (int i = 0; i < 4; ++i) {
      #pragma unroll
      for (int r = 0; r < 4; ++r) {
        const int row = bm + wr + i * 16 + r0 + r;
        if (row < M) {
          float t = acc[i][j][r] + bv;
          if (ACT == 1) t = fmaxf(t, 0.f);
          else if (ACT == 2) t = (t > 0.f) ? t : expm1f(t);
          if (OUTB) Cb[(size_t)row * N + col] = f2b(t);
          else      Cf[(size_t)row * N + col] = t;
        }
      }
    }
  }
}

// ---------------- CSR build ----------------
__global__ void count_deg(const int* __restrict__ dst, int* __restrict__ deg, int E){
  int e = blockIdx.x * blockDim.x + threadIdx.x;
  if (e < E) atomicAdd(&deg[dst[e]], 1);
}

__global__ __launch_bounds__(1024) void scan_offsets(const int* __restrict__ deg, int* __restrict__ offs, int n){
  __shared__ int ws[16];
  const int tid = threadIdx.x, lane = tid & 63, wid = tid >> 6;
  int running = 0;
  for (int base = 0; base < n; base += 1024){
    const int i = base + tid;
    const int v = (i < n) ? deg[i] : 0;
    int x = v;
    #pragma unroll
    for (int s = 1; s < 64; s <<= 1){
      int u = __shfl_up(x, s, 64);
      if (lane >= s) x += u;
    }
    if (lane == 63) ws[wid] = x;
    __syncthreads();
    if (tid < 16){
      int p = ws[tid];
      #pragma unroll
      for (int s = 1; s < 16; s <<= 1){
        int u = __shfl_up(p, s, 64);
        if (tid >= s) p += u;
      }
      ws[tid] = p;   // inclusive over waves
    }
    __syncthreads();
    const int wpre = (wid > 0) ? ws[wid - 1] : 0;
    if (i < n) offs[i] = running + wpre + x - v;   // exclusive
    running += ws[15];
    __syncthreads();
  }
  if (tid == 0) offs[n] = running;
}

// fill CSR: store src and edge_attr (as float4) in dst-sorted position order
__global__ void fill_csr(const int* __restrict__ src, const int* __restrict__ dst,
                         const float* __restrict__ edge_attr,
                         const int* __restrict__ offs, int* __restrict__ cursor,
                         int* __restrict__ csr_src, float* __restrict__ csr_ea, int E){
  int e = blockIdx.x * blockDim.x + threadIdx.x;
  if (e < E){
    int d = dst[e];
    int pos = offs[d] + atomicAdd(&cursor[d], 1);
    csr_src[pos] = src[e];
    *reinterpret_cast<float4*>(csr_ea + (size_t)pos * 4) = ld4(edge_attr + (size_t)e * 4);
  }
}

// ---------------- fused GATv2: 128 threads/node; thread t owns dims [8t, 8t+8); head = t>>4 ----------------
// Halves per-edge duplicated scalar work vs 256-thr version; 4-step 16-lane shfl reduce.
__global__ __launch_bounds__(128) void fused_gat(
    const int* __restrict__ offs, const int* __restrict__ csr_src, const float* __restrict__ csr_ea,
    const float* __restrict__ We, const float* __restrict__ att,
    const ushort_t* __restrict__ xlr, const float* __restrict__ bias,
    ushort_t* __restrict__ out, int N)
{
  const int n = blockIdx.x;
  const int t = threadIdx.x;
  const int d0 = t * 8;

  f32x2 W0[4], W1[4], W2[4], W3[4], AT[4];
  #pragma unroll
  for (int q = 0; q < 4; ++q){
    W0[q] = *reinterpret_cast<const f32x2*>(We + d0 + 2*q);
    W1[q] = *reinterpret_cast<const f32x2*>(We + 1024 + d0 + 2*q);
    W2[q] = *reinterpret_cast<const f32x2*>(We + 2048 + d0 + 2*q);
    W3[q] = *reinterpret_cast<const f32x2*>(We + 3072 + d0 + 2*q);
    AT[q] = *reinterpret_cast<const f32x2*>(att + d0 + 2*q);
  }
  f32x2 xr[4];
  {
    const uint4 xu = *reinterpret_cast<const uint4*>(xlr + (size_t)n * 2048 + 1024 + d0);
    xr[0] = up2(xu.x); xr[1] = up2(xu.y); xr[2] = up2(xu.z); xr[3] = up2(xu.w);
  }

  const int o0 = __builtin_amdgcn_readfirstlane(offs[n]);
  const int o1 = __builtin_amdgcn_readfirstlane(offs[n + 1]);

  f32x2 acc[4];
  #pragma unroll
  for (int q = 0; q < 4; ++q) acc[q] = (f32x2){0.f, 0.f};
  float lsum = 0.f, mcur = -1e30f;

  uint4 xa = {0u,0u,0u,0u}, xb = {0u,0u,0u,0u};
  float eA0=0.f,eA1=0.f,eA2=0.f,eA3=0.f, eB0=0.f,eB1=0.f,eB2=0.f,eB3=0.f;

  auto ldedge = [&](int idx, uint4& xv, float& e0, float& e1, float& e2, float& e3){
    const int s = __builtin_amdgcn_readfirstlane(csr_src[idx]);
    xv = *reinterpret_cast<const uint4*>(xlr + (size_t)s * 2048 + d0);
    const float4 e = ld4(csr_ea + (size_t)idx * 4);
    e0 = rfl(e.x); e1 = rfl(e.y); e2 = rfl(e.z); e3 = rfl(e.w);
  };

  if (o0 < o1)     ldedge(o0,     xa, eA0,eA1,eA2,eA3);
  if (o0 + 1 < o1) ldedge(o0 + 1, xb, eB0,eB1,eB2,eB3);

  int i = o0;
  while (i < o1){
    const uint4 ca = xa; const float a0=eA0,a1=eA1,a2=eA2,a3=eA3;
    const uint4 cb = xb; const float b0=eB0,b1=eB1,b2=eB2,b3=eB3;
    const bool pair = (i + 1 < o1);
    const int ni = i + 2;
    if (ni < o1)     ldedge(ni,     xa, eA0,eA1,eA2,eA3);
    if (ni + 1 < o1) ldedge(ni + 1, xb, eB0,eB1,eB2,eB3);

    f32x2 xav[4] = {up2(ca.x), up2(ca.y), up2(ca.z), up2(ca.w)};
    f32x2 xbv[4] = {up2(cb.x), up2(cb.y), up2(cb.z), up2(cb.w)};

    f32x2 za2 = {0.f,0.f}, zb2 = {0.f,0.f};
    #pragma unroll
    for (int q = 0; q < 4; ++q){
      f32x2 ma = xav[q] + xr[q];
      ma += W0[q]*a0; ma += W1[q]*a1; ma += W2[q]*a2; ma += W3[q]*a3;
      ma = lrelu2(ma);
      za2 += ma * AT[q];
      f32x2 mb = xbv[q] + xr[q];
      mb += W0[q]*b0; mb += W1[q]*b1; mb += W2[q]*b2; mb += W3[q]*b3;
      mb = lrelu2(mb);
      zb2 += mb * AT[q];
    }
    float zA = za2[0] + za2[1];
    float zB = zb2[0] + zb2[1];
    #pragma unroll
    for (int sh = 1; sh <= 8; sh <<= 1){
      zA += __shfl_xor(zA, sh, 64);
      zB += __shfl_xor(zB, sh, 64);
    }

    if (pair){
      const float mn = fmaxf(fmaxf(mcur, zA), zB);
      const float sc = __expf(mcur - mn);
      const float pA = __expf(zA - mn);
      const float pB = __expf(zB - mn);
      lsum = lsum * sc + pA + pB;
      #pragma unroll
      for (int q = 0; q < 4; ++q)
        acc[q] = acc[q] * sc + xav[q] * pA + xbv[q] * pB;
      mcur = mn;
    } else {
      const float mn = fmaxf(mcur, zA);
      const float sc = __expf(mcur - mn);
      const float pA = __expf(zA - mn);
      lsum = lsum * sc + pA;
      #pragma unroll
      for (int q = 0; q < 4; ++q)
        acc[q] = acc[q] * sc + xav[q] * pA;
      mcur = mn;
    }
    i = ni;
  }

  const float r = 1.f / (lsum + EPSV);
  const float4 bv0 = ld4(bias + d0);
  const float4 bv1 = ld4(bias + d0 + 4);
  float o_[8] = {acc[0][0]*r + bv0.x, acc[0][1]*r + bv0.y, acc[1][0]*r + bv0.z, acc[1][1]*r + bv0.w,
                 acc[2][0]*r + bv1.x, acc[2][1]*r + bv1.y, acc[3][0]*r + bv1.z, acc[3][1]*r + bv1.w};
  us8 ov;
  #pragma unroll
  for (int j = 0; j < 8; ++j){
    float v = o_[j];
    v = (v > 0.f) ? v : expm1f(v);
    ov[j] = f2b(v);
  }
  *reinterpret_cast<us8*>(out + (size_t)n * HID + d0) = ov;
}

// ---------------- final matvec + sigmoid: one wave per row ----------------
__global__ __launch_bounds__(256) void mlp_final(const float* __restrict__ h, const float* __restrict__ w,
                                                 const float* __restrict__ b, float* __restrict__ out, int M)
{
  const int row = (int)((blockIdx.x * (size_t)blockDim.x + threadIdx.x) >> 6);
  const int lane = threadIdx.x & 63;
  if (row >= M) return;
  const float2 v  = *reinterpret_cast<const float2*>(&h[(size_t)row * 128 + lane * 2]);
  const float2 ww = *reinterpret_cast<const float2*>(&w[lane * 2]);
  float s = v.x * ww.x + v.y * ww.y;
  #pragma unroll
  for (int m = 1; m <= 32; m <<= 1) s += __shfl_xor(s, m, 64);
  if (lane == 0) out[row] = 1.f / (1.f + expf(-(s + b[0])));
}

extern "C" void kernel_launch(void* const* d_in, const int* in_sizes, int n_in,
                              void* d_out, int out_size, void* d_ws, size_t ws_size,
                              hipStream_t stream)
{
  const float* x        = (const float*)d_in[0];
  const int*   ei       = (const int*)d_in[1];
  const float* edge_attr= (const float*)d_in[2];
  const float* W_in     = (const float*)d_in[3];
  const float* b_in     = (const float*)d_in[4];
  const float* m1_W     = (const float*)d_in[5];
  const float* m1_b     = (const float*)d_in[6];
  const float* m2_W     = (const float*)d_in[7];
  const float* m2_b     = (const float*)d_in[8];
  const float* m3_W     = (const float*)d_in[9];
  const float* m3_b     = (const float*)d_in[10];
  const float* g_Wl[2]  = {(const float*)d_in[11], (const float*)d_in[18]};
  const float* g_bl[2]  = {(const float*)d_in[12], (const float*)d_in[19]};
  const float* g_Wr[2]  = {(const float*)d_in[13], (const float*)d_in[20]};
  const float* g_br[2]  = {(const float*)d_in[14], (const float*)d_in[21]};
  const float* g_We[2]  = {(const float*)d_in[15], (const float*)d_in[22]};
  const float* g_att[2] = {(const float*)d_in[16], (const float*)d_in[23]};
  const float* g_b[2]   = {(const float*)d_in[17], (const float*)d_in[24]};

  const int Nn = in_sizes[0] / 1024;
  const int E  = in_sizes[1] / 2;
  const int* srcv = ei;
  const int* dstv = ei + E;
  float* out = (float*)d_out;

  char* wsp = (char*)d_ws;
  size_t off = 0;
  auto alloc = [&](size_t bytes)->char* {
    char* p = wsp + off;
    off = (off + bytes + 255) & ~(size_t)255;
    return p;
  };
  ushort_t* hbf  = (ushort_t*)alloc((size_t)Nn * HID * 2);
  ushort_t* ubuf = (ushort_t*)alloc((size_t)Nn * HID * 2);       // x bf16, later m1 output
  ushort_t* xlr  = (ushort_t*)alloc((size_t)Nn * 2048 * 2);      // [xl | xr]
  float*    m2f  = (float*)   alloc((size_t)Nn * 128 * 4);
  ushort_t* WinT = (ushort_t*)alloc((size_t)1024 * 1024 * 2);
  ushort_t* Wlr0 = (ushort_t*)alloc((size_t)2048 * 1024 * 2);
  ushort_t* Wlr1 = (ushort_t*)alloc((size_t)2048 * 1024 * 2);
  ushort_t* m1T  = (ushort_t*)alloc((size_t)512 * 1024 * 2);
  ushort_t* m2T  = (ushort_t*)alloc((size_t)128 * 512 * 2);
  float*  biasc  = (float*)   alloc((size_t)2048 * 2 * 4);       // concat biases, both layers
  int* deg    = (int*)alloc((size_t)Nn * 2 * 4);
  int* cursor = deg + Nn;
  int* offs   = (int*)alloc((size_t)(Nn + 1) * 4);
  int* csr_src= (int*)alloc((size_t)E * 4);
  float* csr_ea = (float*)alloc((size_t)E * 4 * 4);
  ushort_t* Wlr[2]  = {Wlr0, Wlr1};
  float*    blr[2]  = {biasc, biasc + 2048};

  // --- weight prep: batched transposes, concat biases ---
  TP5 tp;
  tp.src[0] = W_in;    tp.dst[0] = WinT;
  tp.src[1] = g_Wl[0]; tp.dst[1] = Wlr0;
  tp.src[2] = g_Wr[0]; tp.dst[2] = Wlr0 + 1024*1024;
  tp.src[3] = g_Wl[1]; tp.dst[3] = Wlr1;
  tp.src[4] = g_Wr[1]; tp.dst[4] = Wlr1 + 1024*1024;
  transpose_f2b_5<<<dim3(32, 32, 5), 256, 0, stream>>>(tp);
  transpose_f2b<<<dim3(16, 32), 256, 0, stream>>>(m1_W, m1T, 1024, 512);
  transpose_f2b<<<dim3(4, 16), 256, 0, stream>>>(m2_W, m2T, 512, 128);
  convert_f2b<<<2048, 256, 0, stream>>>(x, ubuf, (size_t)Nn * HID);
  BC4 bc; bc.s[0] = g_bl[0]; bc.s[1] = g_br[0]; bc.s[2] = g_bl[1]; bc.s[3] = g_br[1];
  concat_bias<<<16, 256, 0, stream>>>(bc, biasc);

  // --- CSR by dst ---
  hipMemsetAsync(deg, 0, (size_t)Nn * 2 * 4, stream);
  count_deg<<<(E + 255)/256, 256, 0, stream>>>(dstv, deg, E);
  scan_offsets<<<1, 1024, 0, stream>>>(deg, offs, Nn);
  fill_csr<<<(E + 255)/256, 256, 0, stream>>>(srcv, dstv, edge_attr, offs, cursor, csr_src, csr_ea, E);

  const int MB = (Nn + 127) / 128;
  // h0 = elu(x @ W_in + b_in) -> hbf (bf16)
  gemm_mfma<2, 1><<<dim3(8, MB), 256, 0, stream>>>(ubuf, WinT, b_in, nullptr, hbf, Nn, 1024, 1024);

  for (int L = 0; L < 2; ++L){
    gemm_mfma<0, 1><<<dim3(16, MB), 256, 0, stream>>>(hbf, Wlr[L], blr[L], nullptr, xlr, Nn, 1024, 2048);
    fused_gat<<<Nn, 128, 0, stream>>>(offs, csr_src, csr_ea, g_We[L], g_att[L], xlr, g_b[L], hbf, Nn);
  }

  // MLP
  gemm_mfma<1, 1><<<dim3(4, MB), 256, 0, stream>>>(hbf, m1T, m1_b, nullptr, ubuf, Nn, 1024, 512);
  gemm_mfma<1, 0><<<dim3(1, MB), 256, 0, stream>>>(ubuf, m2T, m2_b, m2f, nullptr, Nn, 512, 128);
  mlp_final<<<((size_t)Nn * 64 + 255)/256, 256, 0, stream>>>(m2f, m3_W, m3_b, out, Nn);
}

// Round 8
// 405.918 us; speedup vs baseline: 5.6431x; 1.0432x over previous
//
#include <hip/hip_runtime.h>
#include <math.h>

constexpr int HID = 1024;
constexpr float NEG_SLOPE = 0.2f;
constexpr float EPSV = 1e-16f;

typedef __bf16 bf16x8 __attribute__((ext_vector_type(8)));
typedef float f32x4 __attribute__((ext_vector_type(4)));
typedef float f32x2 __attribute__((ext_vector_type(2)));
typedef unsigned short us8 __attribute__((ext_vector_type(8)));
typedef unsigned short us4 __attribute__((ext_vector_type(4)));
typedef unsigned short ushort_t;

#define AS1 __attribute__((address_space(1)))
#define AS3 __attribute__((address_space(3)))

__device__ __forceinline__ float4 ld4(const float* p){ return *reinterpret_cast<const float4*>(p); }
__device__ __forceinline__ float b2f(ushort_t u){ return __uint_as_float(((unsigned)u) << 16); }
__device__ __forceinline__ ushort_t f2b(float f){
  unsigned u = __float_as_uint(f);
  return (ushort_t)((u + 0x7FFFu + ((u >> 16) & 1u)) >> 16);
}
__device__ __forceinline__ float rfl(float x){
  return __uint_as_float(__builtin_amdgcn_readfirstlane(__float_as_uint(x)));
}
__device__ __forceinline__ f32x2 up2(unsigned u){
  f32x2 r;
  r[0] = __uint_as_float(u << 16);
  r[1] = __uint_as_float(u & 0xffff0000u);
  return r;
}
__device__ __forceinline__ f32x2 lrelu2(f32x2 v){
  return __builtin_elementwise_max(v, v * NEG_SLOPE);
}

// ---------------- batched weight transpose + f32->bf16 (five 1024x1024 mats) ----------------
struct TP5 { const float* src[5]; ushort_t* dst[5]; };
__global__ __launch_bounds__(256) void transpose_f2b_5(TP5 p){
  const int z = blockIdx.z;
  const float* W = p.src[z];
  ushort_t* WT = p.dst[z];
  __shared__ float tile[32][33];
  const int tx = threadIdx.x & 31, ty = threadIdx.x >> 5;
  const int n0 = blockIdx.x * 32, k0 = blockIdx.y * 32;
  #pragma unroll
  for (int r = 0; r < 32; r += 8)
    tile[ty + r][tx] = W[(size_t)(k0 + ty + r) * 1024 + n0 + tx];
  __syncthreads();
  #pragma unroll
  for (int r = 0; r < 32; r += 8)
    WT[(size_t)(n0 + ty + r) * 1024 + k0 + tx] = f2b(tile[tx][ty + r]);
}

// ---------------- single transpose (for m1/m2) ----------------
__global__ __launch_bounds__(256) void transpose_f2b(const float* __restrict__ W, ushort_t* __restrict__ WT,
                                                     int K, int N){
  __shared__ float tile[32][33];
  const int tx = threadIdx.x & 31, ty = threadIdx.x >> 5;
  const int n0 = blockIdx.x * 32, k0 = blockIdx.y * 32;
  #pragma unroll
  for (int r = 0; r < 32; r += 8)
    tile[ty + r][tx] = W[(size_t)(k0 + ty + r) * N + n0 + tx];
  __syncthreads();
  #pragma unroll
  for (int r = 0; r < 32; r += 8)
    WT[(size_t)(n0 + ty + r) * K + k0 + tx] = f2b(tile[tx][ty + r]);
}

// ---------------- bias concat (4 x 1024 f32) ----------------
struct BC4 { const float* s[4]; };
__global__ void concat_bias(BC4 p, float* __restrict__ dst){
  const int i = blockIdx.x * blockDim.x + threadIdx.x;   // 4096 total
  dst[i] = p.s[i >> 10][i & 1023];
}

// ---------------- f32 -> bf16 elementwise ----------------
__global__ void convert_f2b(const float* __restrict__ in, ushort_t* __restrict__ out, size_t n){
  size_t i = ((size_t)blockIdx.x * blockDim.x + threadIdx.x) * 4;
  const size_t stride = (size_t)gridDim.x * blockDim.x * 4;
  for (; i < n; i += stride){
    const float4 v = ld4(in + i);
    us4 o = {f2b(v.x), f2b(v.y), f2b(v.z), f2b(v.w)};
    *reinterpret_cast<us4*>(out + i) = o;
  }
}

// ---------------- bf16 MFMA GEMM, 128x128 tile, BK=64, 8 waves (32x64 each), ----------------
// 2-phase double-buffered LDS with counted-vmcnt pipeline + coalesced us8 epilogue.
template<int ACT, int OUTB>
__global__ __launch_bounds__(512, 4) void gemm_mfma(
    const ushort_t* __restrict__ A, const ushort_t* __restrict__ BT,
    const float* __restrict__ bias, float* __restrict__ Cf, ushort_t* __restrict__ Cb,
    int M, int K, int N)
{
  __shared__ __align__(16) char smem[65536];
  ushort_t* Asl = (ushort_t*)smem;             // [2][8192] ushorts (16 KB per buf)
  ushort_t* Bsl = (ushort_t*)(smem + 32768);   // [2][8192]
  const int tid = threadIdx.x;
  const int lane = tid & 63, wave = tid >> 6;  // 8 waves
  const int wr = (wave >> 1) * 32;             // 0,32,64,96
  const int wc = (wave & 1) * 64;              // 0,64

  // bijective XCD swizzle
  const int nwg = gridDim.x * gridDim.y;
  int wg = blockIdx.y * gridDim.x + blockIdx.x;
  {
    const int q = nwg >> 3, r = nwg & 7;
    const int xcd = wg & 7, lo = wg >> 3;
    wg = (xcd < r ? xcd * (q + 1) : r * (q + 1) + (xcd - r) * q) + lo;
  }
  const int bm = (wg / gridDim.x) * 128, bn = (wg % gridDim.x) * 128;

  const int mrow = lane & 15;
  const int kof = (lane >> 4) * 8;
  const int r0 = (lane >> 4) * 4;

  f32x4 acc[2][4];
  #pragma unroll
  for (int i = 0; i < 2; ++i)
    #pragma unroll
    for (int j = 0; j < 4; ++j)
      acc[i][j] = (f32x4){0.f, 0.f, 0.f, 0.f};

  // staging: element c = q*512 + tid -> row = c>>3 (0..127), k-slice = (c&7)*8
  const int srow = tid >> 3, ssl = (tid & 7) * 8;
  const int ldst = wave * 512 + lane * 8;      // per-wave-uniform base + lane*16B

  auto stage = [&](int buf, int k0){
    #pragma unroll
    for (int q = 0; q < 2; ++q){
      const int row = q * 64 + srow;
      int arow = bm + row; if (arow > M - 1) arow = M - 1;
      __builtin_amdgcn_global_load_lds(
        (const AS1 unsigned int*)(A + (size_t)arow * K + k0 + ssl),
        (AS3 unsigned int*)(Asl + buf * 8192 + q * 4096 + ldst), 16, 0, 0);
      __builtin_amdgcn_global_load_lds(
        (const AS1 unsigned int*)(BT + (size_t)(bn + row) * K + k0 + ssl),
        (AS3 unsigned int*)(Bsl + buf * 8192 + q * 4096 + ldst), 16, 0, 0);
    }
  };

  auto compute = [&](int buf){
    #pragma unroll
    for (int ks = 0; ks < 2; ++ks){
      bf16x8 af[2], bfr[4];
      #pragma unroll
      for (int i = 0; i < 2; ++i)
        af[i] = *reinterpret_cast<const bf16x8*>(&Asl[buf * 8192 + (wr + i * 16 + mrow) * 64 + ks * 32 + kof]);
      #pragma unroll
      for (int j = 0; j < 4; ++j)
        bfr[j] = *reinterpret_cast<const bf16x8*>(&Bsl[buf * 8192 + (wc + j * 16 + mrow) * 64 + ks * 32 + kof]);
      #pragma unroll
      for (int i = 0; i < 2; ++i)
        #pragma unroll
        for (int j = 0; j < 4; ++j)
          acc[i][j] = __builtin_amdgcn_mfma_f32_16x16x32_bf16(af[i], bfr[j], acc[i][j], 0, 0, 0);
    }
  };

  // prologue
  stage(0, 0);
  asm volatile("s_waitcnt vmcnt(0)" ::: "memory");
  __builtin_amdgcn_s_barrier();

  const int NT = K >> 6;
  int cur = 0;
  for (int t = 0; t < NT; ++t){
    if (t + 1 < NT) stage(cur ^ 1, (t + 1) << 6);   // issue next tile BEFORE compute
    compute(cur);                                    // loads fly under MFMA
    asm volatile("s_waitcnt vmcnt(0)" ::: "memory"); // next tile landed
    __builtin_amdgcn_s_barrier();
    cur ^= 1;
  }

  // ---- epilogue: repack via per-wave LDS region -> coalesced 16B stores ----
  float* ldsF = (float*)smem;                 // 16384 floats; wave region = 2048
  const int wbase = wave * 2048;
  #pragma unroll
  for (int i = 0; i < 2; ++i)
    #pragma unroll
    for (int j = 0; j < 4; ++j)
      #pragma unroll
      for (int r = 0; r < 4; ++r)
        ldsF[wbase + (i * 16 + r0 + r) * 64 + j * 16 + mrow] = acc[i][j][r];
  asm volatile("s_waitcnt lgkmcnt(0)" ::: "memory");

  const int lrow = lane >> 3, lcol = (lane & 7) * 8;
  #pragma unroll
  for (int i2 = 0; i2 < 4; ++i2){
    const int row = bm + wr + i2 * 8 + lrow;
    const int col = bn + wc + lcol;
    if (row < M){
      const f32x4 lo = *reinterpret_cast<const f32x4*>(&ldsF[wbase + (i2 * 8 + lrow) * 64 + lcol]);
      const f32x4 hi = *reinterpret_cast<const f32x4*>(&ldsF[wbase + (i2 * 8 + lrow) * 64 + lcol + 4]);
      const float4 b0 = ld4(bias + col), b1 = ld4(bias + col + 4);
      float v[8] = {lo[0] + b0.x, lo[1] + b0.y, lo[2] + b0.z, lo[3] + b0.w,
                    hi[0] + b1.x, hi[1] + b1.y, hi[2] + b1.z, hi[3] + b1.w};
      #pragma unroll
      for (int u = 0; u < 8; ++u){
        float t2 = v[u];
        if (ACT == 1) t2 = fmaxf(t2, 0.f);
        else if (ACT == 2) t2 = (t2 > 0.f) ? t2 : expm1f(t2);
        v[u] = t2;
      }
      if (OUTB){
        us8 ov;
        #pragma unroll
        for (int u = 0; u < 8; ++u) ov[u] = f2b(v[u]);
        *reinterpret_cast<us8*>(Cb + (size_t)row * N + col) = ov;
      } else {
        *reinterpret_cast<float4*>(Cf + (size_t)row * N + col)     = make_float4(v[0], v[1], v[2], v[3]);
        *reinterpret_cast<float4*>(Cf + (size_t)row * N + col + 4) = make_float4(v[4], v[5], v[6], v[7]);
      }
    }
  }
}

// ---------------- CSR build ----------------
__global__ void count_deg(const int* __restrict__ dst, int* __restrict__ deg, int E){
  int e = blockIdx.x * blockDim.x + threadIdx.x;
  if (e < E) atomicAdd(&deg[dst[e]], 1);
}

__global__ __launch_bounds__(1024) void scan_offsets(const int* __restrict__ deg, int* __restrict__ offs, int n){
  __shared__ int ws[16];
  const int tid = threadIdx.x, lane = tid & 63, wid = tid >> 6;
  int running = 0;
  for (int base = 0; base < n; base += 1024){
    const int i = base + tid;
    const int v = (i < n) ? deg[i] : 0;
    int x = v;
    #pragma unroll
    for (int s = 1; s < 64; s <<= 1){
      int u = __shfl_up(x, s, 64);
      if (lane >= s) x += u;
    }
    if (lane == 63) ws[wid] = x;
    __syncthreads();
    if (tid < 16){
      int p = ws[tid];
      #pragma unroll
      for (int s = 1; s < 16; s <<= 1){
        int u = __shfl_up(p, s, 64);
        if (tid >= s) p += u;
      }
      ws[tid] = p;
    }
    __syncthreads();
    const int wpre = (wid > 0) ? ws[wid - 1] : 0;
    if (i < n) offs[i] = running + wpre + x - v;
    running += ws[15];
    __syncthreads();
  }
  if (tid == 0) offs[n] = running;
}

__global__ void fill_csr(const int* __restrict__ src, const int* __restrict__ dst,
                         const float* __restrict__ edge_attr,
                         const int* __restrict__ offs, int* __restrict__ cursor,
                         int* __restrict__ csr_src, float* __restrict__ csr_ea, int E){
  int e = blockIdx.x * blockDim.x + threadIdx.x;
  if (e < E){
    int d = dst[e];
    int pos = offs[d] + atomicAdd(&cursor[d], 1);
    csr_src[pos] = src[e];
    *reinterpret_cast<float4*>(csr_ea + (size_t)pos * 4) = ld4(edge_attr + (size_t)e * 4);
  }
}

// ---------------- fused GATv2: 128 threads/node; thread t owns dims [8t, 8t+8); head = t>>4 ----------------
__global__ __launch_bounds__(128) void fused_gat(
    const int* __restrict__ offs, const int* __restrict__ csr_src, const float* __restrict__ csr_ea,
    const float* __restrict__ We, const float* __restrict__ att,
    const ushort_t* __restrict__ xlr, const float* __restrict__ bias,
    ushort_t* __restrict__ out, int N)
{
  const int n = blockIdx.x;
  const int t = threadIdx.x;
  const int d0 = t * 8;

  f32x2 W0[4], W1[4], W2[4], W3[4], AT[4];
  #pragma unroll
  for (int q = 0; q < 4; ++q){
    W0[q] = *reinterpret_cast<const f32x2*>(We + d0 + 2*q);
    W1[q] = *reinterpret_cast<const f32x2*>(We + 1024 + d0 + 2*q);
    W2[q] = *reinterpret_cast<const f32x2*>(We + 2048 + d0 + 2*q);
    W3[q] = *reinterpret_cast<const f32x2*>(We + 3072 + d0 + 2*q);
    AT[q] = *reinterpret_cast<const f32x2*>(att + d0 + 2*q);
  }
  f32x2 xr[4];
  {
    const uint4 xu = *reinterpret_cast<const uint4*>(xlr + (size_t)n * 2048 + 1024 + d0);
    xr[0] = up2(xu.x); xr[1] = up2(xu.y); xr[2] = up2(xu.z); xr[3] = up2(xu.w);
  }

  const int o0 = __builtin_amdgcn_readfirstlane(offs[n]);
  const int o1 = __builtin_amdgcn_readfirstlane(offs[n + 1]);

  f32x2 acc[4];
  #pragma unroll
  for (int q = 0; q < 4; ++q) acc[q] = (f32x2){0.f, 0.f};
  float lsum = 0.f, mcur = -1e30f;

  uint4 xa = {0u,0u,0u,0u}, xb = {0u,0u,0u,0u};
  float eA0=0.f,eA1=0.f,eA2=0.f,eA3=0.f, eB0=0.f,eB1=0.f,eB2=0.f,eB3=0.f;

  auto ldedge = [&](int idx, uint4& xv, float& e0, float& e1, float& e2, float& e3){
    const int s = __builtin_amdgcn_readfirstlane(csr_src[idx]);
    xv = *reinterpret_cast<const uint4*>(xlr + (size_t)s * 2048 + d0);
    const float4 e = ld4(csr_ea + (size_t)idx * 4);
    e0 = rfl(e.x); e1 = rfl(e.y); e2 = rfl(e.z); e3 = rfl(e.w);
  };

  if (o0 < o1)     ldedge(o0,     xa, eA0,eA1,eA2,eA3);
  if (o0 + 1 < o1) ldedge(o0 + 1, xb, eB0,eB1,eB2,eB3);

  int i = o0;
  while (i < o1){
    const uint4 ca = xa; const float a0=eA0,a1=eA1,a2=eA2,a3=eA3;
    const uint4 cb = xb; const float b0=eB0,b1=eB1,b2=eB2,b3=eB3;
    const bool pair = (i + 1 < o1);
    const int ni = i + 2;
    if (ni < o1)     ldedge(ni,     xa, eA0,eA1,eA2,eA3);
    if (ni + 1 < o1) ldedge(ni + 1, xb, eB0,eB1,eB2,eB3);

    f32x2 xav[4] = {up2(ca.x), up2(ca.y), up2(ca.z), up2(ca.w)};
    f32x2 xbv[4] = {up2(cb.x), up2(cb.y), up2(cb.z), up2(cb.w)};

    f32x2 za2 = {0.f,0.f}, zb2 = {0.f,0.f};
    #pragma unroll
    for (int q = 0; q < 4; ++q){
      f32x2 ma = xav[q] + xr[q];
      ma += W0[q]*a0; ma += W1[q]*a1; ma += W2[q]*a2; ma += W3[q]*a3;
      ma = lrelu2(ma);
      za2 += ma * AT[q];
      f32x2 mb = xbv[q] + xr[q];
      mb += W0[q]*b0; mb += W1[q]*b1; mb += W2[q]*b2; mb += W3[q]*b3;
      mb = lrelu2(mb);
      zb2 += mb * AT[q];
    }
    float zA = za2[0] + za2[1];
    float zB = zb2[0] + zb2[1];
    #pragma unroll
    for (int sh = 1; sh <= 8; sh <<= 1){
      zA += __shfl_xor(zA, sh, 64);
      zB += __shfl_xor(zB, sh, 64);
    }

    if (pair){
      const float mn = fmaxf(fmaxf(mcur, zA), zB);
      const float sc = __expf(mcur - mn);
      const float pA = __expf(zA - mn);
      const float pB = __expf(zB - mn);
      lsum = lsum * sc + pA + pB;
      #pragma unroll
      for (int q = 0; q < 4; ++q)
        acc[q] = acc[q] * sc + xav[q] * pA + xbv[q] * pB;
      mcur = mn;
    } else {
      const float mn = fmaxf(mcur, zA);
      const float sc = __expf(mcur - mn);
      const float pA = __expf(zA - mn);
      lsum = lsum * sc + pA;
      #pragma unroll
      for (int q = 0; q < 4; ++q)
        acc[q] = acc[q] * sc + xav[q] * pA;
      mcur = mn;
    }
    i = ni;
  }

  const float r = 1.f / (lsum + EPSV);
  const float4 bv0 = ld4(bias + d0);
  const float4 bv1 = ld4(bias + d0 + 4);
  float o_[8] = {acc[0][0]*r + bv0.x, acc[0][1]*r + bv0.y, acc[1][0]*r + bv0.z, acc[1][1]*r + bv0.w,
                 acc[2][0]*r + bv1.x, acc[2][1]*r + bv1.y, acc[3][0]*r + bv1.z, acc[3][1]*r + bv1.w};
  us8 ov;
  #pragma unroll
  for (int j = 0; j < 8; ++j){
    float v = o_[j];
    v = (v > 0.f) ? v : expm1f(v);
    ov[j] = f2b(v);
  }
  *reinterpret_cast<us8*>(out + (size_t)n * HID + d0) = ov;
}

// ---------------- final matvec + sigmoid: one wave per row ----------------
__global__ __launch_bounds__(256) void mlp_final(const float* __restrict__ h, const float* __restrict__ w,
                                                 const float* __restrict__ b, float* __restrict__ out, int M)
{
  const int row = (int)((blockIdx.x * (size_t)blockDim.x + threadIdx.x) >> 6);
  const int lane = threadIdx.x & 63;
  if (row >= M) return;
  const float2 v  = *reinterpret_cast<const float2*>(&h[(size_t)row * 128 + lane * 2]);
  const float2 ww = *reinterpret_cast<const float2*>(&w[lane * 2]);
  float s = v.x * ww.x + v.y * ww.y;
  #pragma unroll
  for (int m = 1; m <= 32; m <<= 1) s += __shfl_xor(s, m, 64);
  if (lane == 0) out[row] = 1.f / (1.f + expf(-(s + b[0])));
}

extern "C" void kernel_launch(void* const* d_in, const int* in_sizes, int n_in,
                              void* d_out, int out_size, void* d_ws, size_t ws_size,
                              hipStream_t stream)
{
  const float* x        = (const float*)d_in[0];
  const int*   ei       = (const int*)d_in[1];
  const float* edge_attr= (const float*)d_in[2];
  const float* W_in     = (const float*)d_in[3];
  const float* b_in     = (const float*)d_in[4];
  const float* m1_W     = (const float*)d_in[5];
  const float* m1_b     = (const float*)d_in[6];
  const float* m2_W     = (const float*)d_in[7];
  const float* m2_b     = (const float*)d_in[8];
  const float* m3_W     = (const float*)d_in[9];
  const float* m3_b     = (const float*)d_in[10];
  const float* g_Wl[2]  = {(const float*)d_in[11], (const float*)d_in[18]};
  const float* g_bl[2]  = {(const float*)d_in[12], (const float*)d_in[19]};
  const float* g_Wr[2]  = {(const float*)d_in[13], (const float*)d_in[20]};
  const float* g_br[2]  = {(const float*)d_in[14], (const float*)d_in[21]};
  const float* g_We[2]  = {(const float*)d_in[15], (const float*)d_in[22]};
  const float* g_att[2] = {(const float*)d_in[16], (const float*)d_in[23]};
  const float* g_b[2]   = {(const float*)d_in[17], (const float*)d_in[24]};

  const int Nn = in_sizes[0] / 1024;
  const int E  = in_sizes[1] / 2;
  const int* srcv = ei;
  const int* dstv = ei + E;
  float* out = (float*)d_out;

  char* wsp = (char*)d_ws;
  size_t off = 0;
  auto alloc = [&](size_t bytes)->char* {
    char* p = wsp + off;
    off = (off + bytes + 255) & ~(size_t)255;
    return p;
  };
  ushort_t* hbf  = (ushort_t*)alloc((size_t)Nn * HID * 2);
  ushort_t* ubuf = (ushort_t*)alloc((size_t)Nn * HID * 2);       // x bf16, later m1 output
  ushort_t* xlr  = (ushort_t*)alloc((size_t)Nn * 2048 * 2);      // [xl | xr]
  float*    m2f  = (float*)   alloc((size_t)Nn * 128 * 4);
  ushort_t* WinT = (ushort_t*)alloc((size_t)1024 * 1024 * 2);
  ushort_t* Wlr0 = (ushort_t*)alloc((size_t)2048 * 1024 * 2);
  ushort_t* Wlr1 = (ushort_t*)alloc((size_t)2048 * 1024 * 2);
  ushort_t* m1T  = (ushort_t*)alloc((size_t)512 * 1024 * 2);
  ushort_t* m2T  = (ushort_t*)alloc((size_t)128 * 512 * 2);
  float*  biasc  = (float*)   alloc((size_t)2048 * 2 * 4);
  int* deg    = (int*)alloc((size_t)Nn * 2 * 4);
  int* cursor = deg + Nn;
  int* offs   = (int*)alloc((size_t)(Nn + 1) * 4);
  int* csr_src= (int*)alloc((size_t)E * 4);
  float* csr_ea = (float*)alloc((size_t)E * 4 * 4);
  ushort_t* Wlr[2]  = {Wlr0, Wlr1};
  float*    blr[2]  = {biasc, biasc + 2048};

  // --- weight prep ---
  TP5 tp;
  tp.src[0] = W_in;    tp.dst[0] = WinT;
  tp.src[1] = g_Wl[0]; tp.dst[1] = Wlr0;
  tp.src[2] = g_Wr[0]; tp.dst[2] = Wlr0 + 1024*1024;
  tp.src[3] = g_Wl[1]; tp.dst[3] = Wlr1;
  tp.src[4] = g_Wr[1]; tp.dst[4] = Wlr1 + 1024*1024;
  transpose_f2b_5<<<dim3(32, 32, 5), 256, 0, stream>>>(tp);
  transpose_f2b<<<dim3(16, 32), 256, 0, stream>>>(m1_W, m1T, 1024, 512);
  transpose_f2b<<<dim3(4, 16), 256, 0, stream>>>(m2_W, m2T, 512, 128);
  convert_f2b<<<2048, 256, 0, stream>>>(x, ubuf, (size_t)Nn * HID);
  BC4 bc; bc.s[0] = g_bl[0]; bc.s[1] = g_br[0]; bc.s[2] = g_bl[1]; bc.s[3] = g_br[1];
  concat_bias<<<16, 256, 0, stream>>>(bc, biasc);

  // --- CSR by dst ---
  hipMemsetAsync(deg, 0, (size_t)Nn * 2 * 4, stream);
  count_deg<<<(E + 255)/256, 256, 0, stream>>>(dstv, deg, E);
  scan_offsets<<<1, 1024, 0, stream>>>(deg, offs, Nn);
  fill_csr<<<(E + 255)/256, 256, 0, stream>>>(srcv, dstv, edge_attr, offs, cursor, csr_src, csr_ea, E);

  const int MB = (Nn + 127) / 128;
  // h0 = elu(x @ W_in + b_in) -> hbf (bf16)
  gemm_mfma<2, 1><<<dim3(8, MB), 512, 0, stream>>>(ubuf, WinT, b_in, nullptr, hbf, Nn, 1024, 1024);

  for (int L = 0; L < 2; ++L){
    gemm_mfma<0, 1><<<dim3(16, MB), 512, 0, stream>>>(hbf, Wlr[L], blr[L], nullptr, xlr, Nn, 1024, 2048);
    fused_gat<<<Nn, 128, 0, stream>>>(offs, csr_src, csr_ea, g_We[L], g_att[L], xlr, g_b[L], hbf, Nn);
  }

  // MLP
  gemm_mfma<1, 1><<<dim3(4, MB), 512, 0, stream>>>(hbf, m1T, m1_b, nullptr, ubuf, Nn, 1024, 512);
  gemm_mfma<1, 0><<<dim3(1, MB), 512, 0, stream>>>(ubuf, m2T, m2_b, m2f, nullptr, Nn, 512, 128);
  mlp_final<<<((size_t)Nn * 64 + 255)/256, 256, 0, stream>>>(m2f, m3_W, m3_b, out, Nn);
}

// Round 9
// 345.379 us; speedup vs baseline: 6.6322x; 1.1753x over previous
//
#include <hip/hip_runtime.h>
#include <math.h>

constexpr int HID = 1024;
constexpr float NEG_SLOPE = 0.2f;
constexpr float EPSV = 1e-16f;

typedef __bf16 bf16x8 __attribute__((ext_vector_type(8)));
typedef float f32x4 __attribute__((ext_vector_type(4)));
typedef float f32x2 __attribute__((ext_vector_type(2)));
typedef unsigned short us8 __attribute__((ext_vector_type(8)));
typedef unsigned short us4 __attribute__((ext_vector_type(4)));
typedef unsigned short ushort_t;

#define AS1 __attribute__((address_space(1)))
#define AS3 __attribute__((address_space(3)))

__device__ __forceinline__ float4 ld4(const float* p){ return *reinterpret_cast<const float4*>(p); }
__device__ __forceinline__ float b2f(ushort_t u){ return __uint_as_float(((unsigned)u) << 16); }
__device__ __forceinline__ ushort_t f2b(float f){
  unsigned u = __float_as_uint(f);
  return (ushort_t)((u + 0x7FFFu + ((u >> 16) & 1u)) >> 16);
}
__device__ __forceinline__ float rfl(float x){
  return __uint_as_float(__builtin_amdgcn_readfirstlane(__float_as_uint(x)));
}
__device__ __forceinline__ f32x2 up2(unsigned u){
  f32x2 r;
  r[0] = __uint_as_float(u << 16);
  r[1] = __uint_as_float(u & 0xffff0000u);
  return r;
}
__device__ __forceinline__ f32x2 lrelu2(f32x2 v){
  return __builtin_elementwise_max(v, v * NEG_SLOPE);
}

// ---------------- batched weight transpose + f32->bf16 (five 1024x1024 mats) ----------------
struct TP5 { const float* src[5]; ushort_t* dst[5]; };
__global__ __launch_bounds__(256) void transpose_f2b_5(TP5 p){
  const int z = blockIdx.z;
  const float* W = p.src[z];
  ushort_t* WT = p.dst[z];
  __shared__ float tile[32][33];
  const int tx = threadIdx.x & 31, ty = threadIdx.x >> 5;
  const int n0 = blockIdx.x * 32, k0 = blockIdx.y * 32;
  #pragma unroll
  for (int r = 0; r < 32; r += 8)
    tile[ty + r][tx] = W[(size_t)(k0 + ty + r) * 1024 + n0 + tx];
  __syncthreads();
  #pragma unroll
  for (int r = 0; r < 32; r += 8)
    WT[(size_t)(n0 + ty + r) * 1024 + k0 + tx] = f2b(tile[tx][ty + r]);
}

// ---------------- single transpose (for m1/m2) ----------------
__global__ __launch_bounds__(256) void transpose_f2b(const float* __restrict__ W, ushort_t* __restrict__ WT,
                                                     int K, int N){
  __shared__ float tile[32][33];
  const int tx = threadIdx.x & 31, ty = threadIdx.x >> 5;
  const int n0 = blockIdx.x * 32, k0 = blockIdx.y * 32;
  #pragma unroll
  for (int r = 0; r < 32; r += 8)
    tile[ty + r][tx] = W[(size_t)(k0 + ty + r) * N + n0 + tx];
  __syncthreads();
  #pragma unroll
  for (int r = 0; r < 32; r += 8)
    WT[(size_t)(n0 + ty + r) * K + k0 + tx] = f2b(tile[tx][ty + r]);
}

// ---------------- bias concat (4 x 1024 f32) ----------------
struct BC4 { const float* s[4]; };
__global__ void concat_bias(BC4 p, float* __restrict__ dst){
  const int i = blockIdx.x * blockDim.x + threadIdx.x;   // 4096 total
  dst[i] = p.s[i >> 10][i & 1023];
}

// ---------------- f32 -> bf16 elementwise ----------------
__global__ void convert_f2b(const float* __restrict__ in, ushort_t* __restrict__ out, size_t n){
  size_t i = ((size_t)blockIdx.x * blockDim.x + threadIdx.x) * 4;
  const size_t stride = (size_t)gridDim.x * blockDim.x * 4;
  for (; i < n; i += stride){
    const float4 v = ld4(in + i);
    us4 o = {f2b(v.x), f2b(v.y), f2b(v.z), f2b(v.w)};
    *reinterpret_cast<us4*>(out + i) = o;
  }
}

// ---------------- bf16 MFMA GEMM, 128x128 tile, BK=64, 8 waves (32x64 each) ----------------
// 2-phase double-buffered LDS + T2 XOR swizzle (pre-swizzled global src, swizzled ds_read)
// + coalesced us8 epilogue via LDS repack.
template<int ACT, int OUTB>
__global__ __launch_bounds__(512, 4) void gemm_mfma(
    const ushort_t* __restrict__ A, const ushort_t* __restrict__ BT,
    const float* __restrict__ bias, float* __restrict__ Cf, ushort_t* __restrict__ Cb,
    int M, int K, int N)
{
  __shared__ __align__(16) char smem[65536];
  ushort_t* Asl = (ushort_t*)smem;             // [2][8192] ushorts (16 KB per buf)
  ushort_t* Bsl = (ushort_t*)(smem + 32768);   // [2][8192]
  const int tid = threadIdx.x;
  const int lane = tid & 63, wave = tid >> 6;  // 8 waves
  const int wr = (wave >> 1) * 32;             // 0,32,64,96
  const int wc = (wave & 1) * 64;              // 0,64

  // bijective XCD swizzle
  const int nwg = gridDim.x * gridDim.y;
  int wg = blockIdx.y * gridDim.x + blockIdx.x;
  {
    const int q = nwg >> 3, r = nwg & 7;
    const int xcd = wg & 7, lo = wg >> 3;
    wg = (xcd < r ? xcd * (q + 1) : r * (q + 1) + (xcd - r) * q) + lo;
  }
  const int bm = (wg / gridDim.x) * 128, bn = (wg % gridDim.x) * 128;

  const int mrow = lane & 15;
  const int r0 = (lane >> 4) * 4;

  f32x4 acc[2][4];
  #pragma unroll
  for (int i = 0; i < 2; ++i)
    #pragma unroll
    for (int j = 0; j < 4; ++j)
      acc[i][j] = (f32x4){0.f, 0.f, 0.f, 0.f};

  // staging map: LDS slot (row, kslice=lane&7) <- global (row, kslice ^ (row&7)).
  // row = wave*8 + (lane>>3); row&7 == (lane>>3), so source k-slice is lane-computable.
  const int srow = tid >> 3;
  const int ssl = (((lane & 7) ^ (lane >> 3))) * 8;   // pre-swizzled global k-slice
  const int ldst = wave * 512 + lane * 8;             // linear LDS dest (wave-uniform base + lane*16B)

  auto stage = [&](int buf, int k0){
    #pragma unroll
    for (int q = 0; q < 2; ++q){
      const int row = q * 64 + srow;
      int arow = bm + row; if (arow > M - 1) arow = M - 1;
      __builtin_amdgcn_global_load_lds(
        (const AS1 unsigned int*)(A + (size_t)arow * K + k0 + ssl),
        (AS3 unsigned int*)(Asl + buf * 8192 + q * 4096 + ldst), 16, 0, 0);
      __builtin_amdgcn_global_load_lds(
        (const AS1 unsigned int*)(BT + (size_t)(bn + row) * K + k0 + ssl),
        (AS3 unsigned int*)(Bsl + buf * 8192 + q * 4096 + ldst), 16, 0, 0);
    }
  };

  // fragment read: global (row, slice) lives at LDS slot (row, slice ^ (row&7))
  const int kslice = (lane >> 4);   // 0..3 within a 32-K half (slice = ks*4 + kslice)
  auto compute = [&](int buf){
    #pragma unroll
    for (int ks = 0; ks < 2; ++ks){
      bf16x8 af[2], bfr[4];
      #pragma unroll
      for (int i = 0; i < 2; ++i){
        const int row = wr + i * 16 + mrow;
        const int sl = (ks * 4 + kslice) ^ (row & 7);
        af[i] = *reinterpret_cast<const bf16x8*>(&Asl[buf * 8192 + row * 64 + sl * 8]);
      }
      #pragma unroll
      for (int j = 0; j < 4; ++j){
        const int row = wc + j * 16 + mrow;
        const int sl = (ks * 4 + kslice) ^ (row & 7);
        bfr[j] = *reinterpret_cast<const bf16x8*>(&Bsl[buf * 8192 + row * 64 + sl * 8]);
      }
      #pragma unroll
      for (int i = 0; i < 2; ++i)
        #pragma unroll
        for (int j = 0; j < 4; ++j)
          acc[i][j] = __builtin_amdgcn_mfma_f32_16x16x32_bf16(af[i], bfr[j], acc[i][j], 0, 0, 0);
    }
  };

  // prologue
  stage(0, 0);
  asm volatile("s_waitcnt vmcnt(0)" ::: "memory");
  __builtin_amdgcn_s_barrier();

  const int NT = K >> 6;
  int cur = 0;
  for (int t = 0; t < NT; ++t){
    if (t + 1 < NT) stage(cur ^ 1, (t + 1) << 6);   // issue next tile BEFORE compute
    compute(cur);                                    // loads fly under MFMA
    asm volatile("s_waitcnt vmcnt(0)" ::: "memory"); // next tile landed
    __builtin_amdgcn_s_barrier();
    cur ^= 1;
  }

  // ---- epilogue: repack via per-wave LDS region -> coalesced 16B stores ----
  float* ldsF = (float*)smem;                 // 16384 floats; wave region = 2048
  const int wbase = wave * 2048;
  #pragma unroll
  for (int i = 0; i < 2; ++i)
    #pragma unroll
    for (int j = 0; j < 4; ++j)
      #pragma unroll
      for (int r = 0; r < 4; ++r)
        ldsF[wbase + (i * 16 + r0 + r) * 64 + j * 16 + mrow] = acc[i][j][r];
  asm volatile("s_waitcnt lgkmcnt(0)" ::: "memory");

  const int lrow = lane >> 3, lcol = (lane & 7) * 8;
  #pragma unroll
  for (int i2 = 0; i2 < 4; ++i2){
    const int row = bm + wr + i2 * 8 + lrow;
    const int col = bn + wc + lcol;
    if (row < M){
      const f32x4 lo = *reinterpret_cast<const f32x4*>(&ldsF[wbase + (i2 * 8 + lrow) * 64 + lcol]);
      const f32x4 hi = *reinterpret_cast<const f32x4*>(&ldsF[wbase + (i2 * 8 + lrow) * 64 + lcol + 4]);
      const float4 b0 = ld4(bias + col), b1 = ld4(bias + col + 4);
      float v[8] = {lo[0] + b0.x, lo[1] + b0.y, lo[2] + b0.z, lo[3] + b0.w,
                    hi[0] + b1.x, hi[1] + b1.y, hi[2] + b1.z, hi[3] + b1.w};
      #pragma unroll
      for (int u = 0; u < 8; ++u){
        float t2 = v[u];
        if (ACT == 1) t2 = fmaxf(t2, 0.f);
        else if (ACT == 2) t2 = (t2 > 0.f) ? t2 : expm1f(t2);
        v[u] = t2;
      }
      if (OUTB){
        us8 ov;
        #pragma unroll
        for (int u = 0; u < 8; ++u) ov[u] = f2b(v[u]);
        *reinterpret_cast<us8*>(Cb + (size_t)row * N + col) = ov;
      } else {
        *reinterpret_cast<float4*>(Cf + (size_t)row * N + col)     = make_float4(v[0], v[1], v[2], v[3]);
        *reinterpret_cast<float4*>(Cf + (size_t)row * N + col + 4) = make_float4(v[4], v[5], v[6], v[7]);
      }
    }
  }
}

// ---------------- CSR build ----------------
__global__ void count_deg(const int* __restrict__ dst, int* __restrict__ deg, int E){
  int e = blockIdx.x * blockDim.x + threadIdx.x;
  if (e < E) atomicAdd(&deg[dst[e]], 1);
}

__global__ __launch_bounds__(1024) void scan_offsets(const int* __restrict__ deg, int* __restrict__ offs, int n){
  __shared__ int ws[16];
  const int tid = threadIdx.x, lane = tid & 63, wid = tid >> 6;
  int running = 0;
  for (int base = 0; base < n; base += 1024){
    const int i = base + tid;
    const int v = (i < n) ? deg[i] : 0;
    int x = v;
    #pragma unroll
    for (int s = 1; s < 64; s <<= 1){
      int u = __shfl_up(x, s, 64);
      if (lane >= s) x += u;
    }
    if (lane == 63) ws[wid] = x;
    __syncthreads();
    if (tid < 16){
      int p = ws[tid];
      #pragma unroll
      for (int s = 1; s < 16; s <<= 1){
        int u = __shfl_up(p, s, 64);
        if (tid >= s) p += u;
      }
      ws[tid] = p;
    }
    __syncthreads();
    const int wpre = (wid > 0) ? ws[wid - 1] : 0;
    if (i < n) offs[i] = running + wpre + x - v;
    running += ws[15];
    __syncthreads();
  }
  if (tid == 0) offs[n] = running;
}

__global__ void fill_csr(const int* __restrict__ src, const int* __restrict__ dst,
                         const float* __restrict__ edge_attr,
                         const int* __restrict__ offs, int* __restrict__ cursor,
                         int* __restrict__ csr_src, float* __restrict__ csr_ea, int E){
  int e = blockIdx.x * blockDim.x + threadIdx.x;
  if (e < E){
    int d = dst[e];
    int pos = offs[d] + atomicAdd(&cursor[d], 1);
    csr_src[pos] = src[e];
    *reinterpret_cast<float4*>(csr_ea + (size_t)pos * 4) = ld4(edge_attr + (size_t)e * 4);
  }
}

// ---------------- fused GATv2: 128 threads/node; thread t owns dims [8t, 8t+8); head = t>>4 ----------------
__global__ __launch_bounds__(128) void fused_gat(
    const int* __restrict__ offs, const int* __restrict__ csr_src, const float* __restrict__ csr_ea,
    const float* __restrict__ We, const float* __restrict__ att,
    const ushort_t* __restrict__ xlr, const float* __restrict__ bias,
    ushort_t* __restrict__ out, int N)
{
  const int n = blockIdx.x;
  const int t = threadIdx.x;
  const int d0 = t * 8;

  f32x2 W0[4], W1[4], W2[4], W3[4], AT[4];
  #pragma unroll
  for (int q = 0; q < 4; ++q){
    W0[q] = *reinterpret_cast<const f32x2*>(We + d0 + 2*q);
    W1[q] = *reinterpret_cast<const f32x2*>(We + 1024 + d0 + 2*q);
    W2[q] = *reinterpret_cast<const f32x2*>(We + 2048 + d0 + 2*q);
    W3[q] = *reinterpret_cast<const f32x2*>(We + 3072 + d0 + 2*q);
    AT[q] = *reinterpret_cast<const f32x2*>(att + d0 + 2*q);
  }
  f32x2 xr[4];
  {
    const uint4 xu = *reinterpret_cast<const uint4*>(xlr + (size_t)n * 2048 + 1024 + d0);
    xr[0] = up2(xu.x); xr[1] = up2(xu.y); xr[2] = up2(xu.z); xr[3] = up2(xu.w);
  }

  const int o0 = __builtin_amdgcn_readfirstlane(offs[n]);
  const int o1 = __builtin_amdgcn_readfirstlane(offs[n + 1]);

  f32x2 acc[4];
  #pragma unroll
  for (int q = 0; q < 4; ++q) acc[q] = (f32x2){0.f, 0.f};
  float lsum = 0.f, mcur = -1e30f;

  uint4 xa = {0u,0u,0u,0u}, xb = {0u,0u,0u,0u};
  float eA0=0.f,eA1=0.f,eA2=0.f,eA3=0.f, eB0=0.f,eB1=0.f,eB2=0.f,eB3=0.f;

  auto ldedge = [&](int idx, uint4& xv, float& e0, float& e1, float& e2, float& e3){
    const int s = __builtin_amdgcn_readfirstlane(csr_src[idx]);
    xv = *reinterpret_cast<const uint4*>(xlr + (size_t)s * 2048 + d0);
    const float4 e = ld4(csr_ea + (size_t)idx * 4);
    e0 = rfl(e.x); e1 = rfl(e.y); e2 = rfl(e.z); e3 = rfl(e.w);
  };

  if (o0 < o1)     ldedge(o0,     xa, eA0,eA1,eA2,eA3);
  if (o0 + 1 < o1) ldedge(o0 + 1, xb, eB0,eB1,eB2,eB3);

  int i = o0;
  while (i < o1){
    const uint4 ca = xa; const float a0=eA0,a1=eA1,a2=eA2,a3=eA3;
    const uint4 cb = xb; const float b0=eB0,b1=eB1,b2=eB2,b3=eB3;
    const bool pair = (i + 1 < o1);
    const int ni = i + 2;
    if (ni < o1)     ldedge(ni,     xa, eA0,eA1,eA2,eA3);
    if (ni + 1 < o1) ldedge(ni + 1, xb, eB0,eB1,eB2,eB3);

    f32x2 xav[4] = {up2(ca.x), up2(ca.y), up2(ca.z), up2(ca.w)};
    f32x2 xbv[4] = {up2(cb.x), up2(cb.y), up2(cb.z), up2(cb.w)};

    f32x2 za2 = {0.f,0.f}, zb2 = {0.f,0.f};
    #pragma unroll
    for (int q = 0; q < 4; ++q){
      f32x2 ma = xav[q] + xr[q];
      ma += W0[q]*a0; ma += W1[q]*a1; ma += W2[q]*a2; ma += W3[q]*a3;
      ma = lrelu2(ma);
      za2 += ma * AT[q];
      f32x2 mb = xbv[q] + xr[q];
      mb += W0[q]*b0; mb += W1[q]*b1; mb += W2[q]*b2; mb += W3[q]*b3;
      mb = lrelu2(mb);
      zb2 += mb * AT[q];
    }
    float zA = za2[0] + za2[1];
    float zB = zb2[0] + zb2[1];
    #pragma unroll
    for (int sh = 1; sh <= 8; sh <<= 1){
      zA += __shfl_xor(zA, sh, 64);
      zB += __shfl_xor(zB, sh, 64);
    }

    if (pair){
      const float mn = fmaxf(fmaxf(mcur, zA), zB);
      const float sc = __expf(mcur - mn);
      const float pA = __expf(zA - mn);
      const float pB = __expf(zB - mn);
      lsum = lsum * sc + pA + pB;
      #pragma unroll
      for (int q = 0; q < 4; ++q)
        acc[q] = acc[q] * sc + xav[q] * pA + xbv[q] * pB;
      mcur = mn;
    } else {
      const float mn = fmaxf(mcur, zA);
      const float sc = __expf(mcur - mn);
      const float pA = __expf(zA - mn);
      lsum = lsum * sc + pA;
      #pragma unroll
      for (int q = 0; q < 4; ++q)
        acc[q] = acc[q] * sc + xav[q] * pA;
      mcur = mn;
    }
    i = ni;
  }

  const float r = 1.f / (lsum + EPSV);
  const float4 bv0 = ld4(bias + d0);
  const float4 bv1 = ld4(bias + d0 + 4);
  float o_[8] = {acc[0][0]*r + bv0.x, acc[0][1]*r + bv0.y, acc[1][0]*r + bv0.z, acc[1][1]*r + bv0.w,
                 acc[2][0]*r + bv1.x, acc[2][1]*r + bv1.y, acc[3][0]*r + bv1.z, acc[3][1]*r + bv1.w};
  us8 ov;
  #pragma unroll
  for (int j = 0; j < 8; ++j){
    float v = o_[j];
    v = (v > 0.f) ? v : expm1f(v);
    ov[j] = f2b(v);
  }
  *reinterpret_cast<us8*>(out + (size_t)n * HID + d0) = ov;
}

// ---------------- final matvec + sigmoid: one wave per row ----------------
__global__ __launch_bounds__(256) void mlp_final(const float* __restrict__ h, const float* __restrict__ w,
                                                 const float* __restrict__ b, float* __restrict__ out, int M)
{
  const int row = (int)((blockIdx.x * (size_t)blockDim.x + threadIdx.x) >> 6);
  const int lane = threadIdx.x & 63;
  if (row >= M) return;
  const float2 v  = *reinterpret_cast<const float2*>(&h[(size_t)row * 128 + lane * 2]);
  const float2 ww = *reinterpret_cast<const float2*>(&w[lane * 2]);
  float s = v.x * ww.x + v.y * ww.y;
  #pragma unroll
  for (int m = 1; m <= 32; m <<= 1) s += __shfl_xor(s, m, 64);
  if (lane == 0) out[row] = 1.f / (1.f + expf(-(s + b[0])));
}

extern "C" void kernel_launch(void* const* d_in, const int* in_sizes, int n_in,
                              void* d_out, int out_size, void* d_ws, size_t ws_size,
                              hipStream_t stream)
{
  const float* x        = (const float*)d_in[0];
  const int*   ei       = (const int*)d_in[1];
  const float* edge_attr= (const float*)d_in[2];
  const float* W_in     = (const float*)d_in[3];
  const float* b_in     = (const float*)d_in[4];
  const float* m1_W     = (const float*)d_in[5];
  const float* m1_b     = (const float*)d_in[6];
  const float* m2_W     = (const float*)d_in[7];
  const float* m2_b     = (const float*)d_in[8];
  const float* m3_W     = (const float*)d_in[9];
  const float* m3_b     = (const float*)d_in[10];
  const float* g_Wl[2]  = {(const float*)d_in[11], (const float*)d_in[18]};
  const float* g_bl[2]  = {(const float*)d_in[12], (const float*)d_in[19]};
  const float* g_Wr[2]  = {(const float*)d_in[13], (const float*)d_in[20]};
  const float* g_br[2]  = {(const float*)d_in[14], (const float*)d_in[21]};
  const float* g_We[2]  = {(const float*)d_in[15], (const float*)d_in[22]};
  const float* g_att[2] = {(const float*)d_in[16], (const float*)d_in[23]};
  const float* g_b[2]   = {(const float*)d_in[17], (const float*)d_in[24]};

  const int Nn = in_sizes[0] / 1024;
  const int E  = in_sizes[1] / 2;
  const int* srcv = ei;
  const int* dstv = ei + E;
  float* out = (float*)d_out;

  char* wsp = (char*)d_ws;
  size_t off = 0;
  auto alloc = [&](size_t bytes)->char* {
    char* p = wsp + off;
    off = (off + bytes + 255) & ~(size_t)255;
    return p;
  };
  ushort_t* hbf  = (ushort_t*)alloc((size_t)Nn * HID * 2);
  ushort_t* ubuf = (ushort_t*)alloc((size_t)Nn * HID * 2);       // x bf16, later m1 output
  ushort_t* xlr  = (ushort_t*)alloc((size_t)Nn * 2048 * 2);      // [xl | xr]
  float*    m2f  = (float*)   alloc((size_t)Nn * 128 * 4);
  ushort_t* WinT = (ushort_t*)alloc((size_t)1024 * 1024 * 2);
  ushort_t* Wlr0 = (ushort_t*)alloc((size_t)2048 * 1024 * 2);
  ushort_t* Wlr1 = (ushort_t*)alloc((size_t)2048 * 1024 * 2);
  ushort_t* m1T  = (ushort_t*)alloc((size_t)512 * 1024 * 2);
  ushort_t* m2T  = (ushort_t*)alloc((size_t)128 * 512 * 2);
  float*  biasc  = (float*)   alloc((size_t)2048 * 2 * 4);
  int* deg    = (int*)alloc((size_t)Nn * 2 * 4);
  int* cursor = deg + Nn;
  int* offs   = (int*)alloc((size_t)(Nn + 1) * 4);
  int* csr_src= (int*)alloc((size_t)E * 4);
  float* csr_ea = (float*)alloc((size_t)E * 4 * 4);
  ushort_t* Wlr[2]  = {Wlr0, Wlr1};
  float*    blr[2]  = {biasc, biasc + 2048};

  // --- weight prep ---
  TP5 tp;
  tp.src[0] = W_in;    tp.dst[0] = WinT;
  tp.src[1] = g_Wl[0]; tp.dst[1] = Wlr0;
  tp.src[2] = g_Wr[0]; tp.dst[2] = Wlr0 + 1024*1024;
  tp.src[3] = g_Wl[1]; tp.dst[3] = Wlr1;
  tp.src[4] = g_Wr[1]; tp.dst[4] = Wlr1 + 1024*1024;
  transpose_f2b_5<<<dim3(32, 32, 5), 256, 0, stream>>>(tp);
  transpose_f2b<<<dim3(16, 32), 256, 0, stream>>>(m1_W, m1T, 1024, 512);
  transpose_f2b<<<dim3(4, 16), 256, 0, stream>>>(m2_W, m2T, 512, 128);
  convert_f2b<<<2048, 256, 0, stream>>>(x, ubuf, (size_t)Nn * HID);
  BC4 bc; bc.s[0] = g_bl[0]; bc.s[1] = g_br[0]; bc.s[2] = g_bl[1]; bc.s[3] = g_br[1];
  concat_bias<<<16, 256, 0, stream>>>(bc, biasc);

  // --- CSR by dst ---
  hipMemsetAsync(deg, 0, (size_t)Nn * 2 * 4, stream);
  count_deg<<<(E + 255)/256, 256, 0, stream>>>(dstv, deg, E);
  scan_offsets<<<1, 1024, 0, stream>>>(deg, offs, Nn);
  fill_csr<<<(E + 255)/256, 256, 0, stream>>>(srcv, dstv, edge_attr, offs, cursor, csr_src, csr_ea, E);

  const int MB = (Nn + 127) / 128;
  // h0 = elu(x @ W_in + b_in) -> hbf (bf16)
  gemm_mfma<2, 1><<<dim3(8, MB), 512, 0, stream>>>(ubuf, WinT, b_in, nullptr, hbf, Nn, 1024, 1024);

  for (int L = 0; L < 2; ++L){
    gemm_mfma<0, 1><<<dim3(16, MB), 512, 0, stream>>>(hbf, Wlr[L], blr[L], nullptr, xlr, Nn, 1024, 2048);
    fused_gat<<<Nn, 128, 0, stream>>>(offs, csr_src, csr_ea, g_We[L], g_att[L], xlr, g_b[L], hbf, Nn);
  }

  // MLP
  gemm_mfma<1, 1><<<dim3(4, MB), 512, 0, stream>>>(hbf, m1T, m1_b, nullptr, ubuf, Nn, 1024, 512);
  gemm_mfma<1, 0><<<dim3(1, MB), 512, 0, stream>>>(ubuf, m2T, m2_b, m2f, nullptr, Nn, 512, 128);
  mlp_final<<<((size_t)Nn * 64 + 255)/256, 256, 0, stream>>>(m2f, m3_W, m3_b, out, Nn);
}